// Round 9
// baseline (531.049 us; speedup 1.0000x reference)
//
#include <hip/hip_runtime.h>
#include <math.h>

// Deformable-DETR encoder, 2 layers. Round 9: mgemm_ln back to 64-row tiles,
// BK=128 K-loops for the grid-bound N=256 GEMMs (half the barrier drains;
// LDS is free since grid, not LDS, binds occupancy there).

#define S_TOT 13294
#define BATCH 2
#define M_TOT (BATCH * S_TOT)     // 26588
#define M_PAD 26624               // 208*128 = 416*64

typedef __attribute__((ext_vector_type(8))) short short8;
typedef __attribute__((ext_vector_type(4))) float floatx4;
typedef __attribute__((ext_vector_type(2))) float floatx2;

#define AS1C(p) ((const __attribute__((address_space(1))) void*)(p))
#define AS3(p)  ((__attribute__((address_space(3))) void*)(p))

static __device__ __forceinline__ unsigned short f2bf(float x) {
    union { float f; unsigned u; } v; v.f = x;
    unsigned r = v.u + 0x7FFFu + ((v.u >> 16) & 1u);
    return (unsigned short)(r >> 16);
}
static __device__ __forceinline__ float bflo(unsigned u) {
    union { unsigned u; float f; } v; v.u = u << 16; return v.f;
}
static __device__ __forceinline__ float bfhi(unsigned u) {
    union { unsigned u; float f; } v; v.u = u & 0xFFFF0000u; return v.f;
}

// ---------------------------------------------------------------------------
// bf16 MFMA GEMM, BK = NC*32. TM=128: 4 waves 2x2 of 64x64. TM=64: 4 waves
// 64x32. PROJ epilogue: col<256 -> bf16 Cb[.,256]; col>=256 -> bf16 Cb2[.,384].
// ---------------------------------------------------------------------------
template<int TM, int NC, bool RELU, bool RES, bool F32OUT, bool BF16OUT, bool PROJ>
__global__ __launch_bounds__(256)
void mgemm(const unsigned short* __restrict__ A,
           const unsigned short* __restrict__ BT,
           const float* __restrict__ bias,
           const float* __restrict__ bias2,
           const float* __restrict__ bias3,
           const float* __restrict__ R,
           float* __restrict__ Cf,
           unsigned short* __restrict__ Cb,
           unsigned short* __restrict__ Cb2,
           int M, int N, int K)
{
    constexpr int WM = (TM == 128) ? 2 : 1;
    constexpr int WN = 4 / WM;
    constexpr int MI = TM / (WM * 16);
    constexpr int NI = 128 / (WN * 16);
    __shared__ __align__(16) unsigned short smemA[NC * TM * 32];
    __shared__ __align__(16) unsigned short smemB[NC * 128 * 32];
    const int tid  = threadIdx.x;
    const int lane = tid & 63;
    const int w    = tid >> 6;
    const int wm   = w % WM, wn = w / WM;
    const int lr   = lane & 15, quad = lane >> 4;
    const int bm   = blockIdx.y * TM;
    const int bn   = blockIdx.x * 128;

    floatx4 acc[MI][NI];
    #pragma unroll
    for (int i = 0; i < MI; ++i)
        #pragma unroll
        for (int j = 0; j < NI; ++j)
            acc[i][j] = (floatx4){0.f, 0.f, 0.f, 0.f};

    const int srow = lane >> 2;
    const int selt = (lane & 3) << 3;

    for (int k0 = 0; k0 < K; k0 += NC * 32) {
        #pragma unroll
        for (int c = 0; c < NC; ++c) {
            if (TM == 128) {
                #pragma unroll
                for (int jj = 0; jj < 2; ++jj) {
                    const int j = 2 * w + jj;
                    const unsigned short* ga = A  + (size_t)(bm + j * 16 + srow) * K + k0 + c * 32 + selt;
                    const unsigned short* gb = BT + (size_t)(bn + j * 16 + srow) * K + k0 + c * 32 + selt;
                    __builtin_amdgcn_global_load_lds(AS1C(ga), AS3(smemA + c * (TM * 32) + j * 512), 16, 0, 0);
                    __builtin_amdgcn_global_load_lds(AS1C(gb), AS3(smemB + c * 4096 + j * 512), 16, 0, 0);
                }
            } else {
                const unsigned short* ga = A + (size_t)(bm + w * 16 + srow) * K + k0 + c * 32 + selt;
                __builtin_amdgcn_global_load_lds(AS1C(ga), AS3(smemA + c * (TM * 32) + w * 512), 16, 0, 0);
                #pragma unroll
                for (int jj = 0; jj < 2; ++jj) {
                    const int j = 2 * w + jj;
                    const unsigned short* gb = BT + (size_t)(bn + j * 16 + srow) * K + k0 + c * 32 + selt;
                    __builtin_amdgcn_global_load_lds(AS1C(gb), AS3(smemB + c * 4096 + j * 512), 16, 0, 0);
                }
            }
        }
        __syncthreads();

        #pragma unroll
        for (int c = 0; c < NC; ++c) {
            short8 av[MI], bv[NI];
            #pragma unroll
            for (int mi = 0; mi < MI; ++mi)
                av[mi] = *(const short8*)&smemA[c * (TM * 32) + (wm * MI * 16 + mi * 16 + lr) * 32 + quad * 8];
            #pragma unroll
            for (int ni = 0; ni < NI; ++ni)
                bv[ni] = *(const short8*)&smemB[c * 4096 + (wn * NI * 16 + ni * 16 + lr) * 32 + quad * 8];
            #pragma unroll
            for (int mi = 0; mi < MI; ++mi)
                #pragma unroll
                for (int ni = 0; ni < NI; ++ni)
                    acc[mi][ni] = __builtin_amdgcn_mfma_f32_16x16x32_bf16(
                        av[mi], bv[ni], acc[mi][ni], 0, 0, 0);
        }
        __syncthreads();
    }

    #pragma unroll
    for (int mi = 0; mi < MI; ++mi) {
        #pragma unroll
        for (int ni = 0; ni < NI; ++ni) {
            #pragma unroll
            for (int r = 0; r < 4; ++r) {
                const int row = bm + wm * MI * 16 + mi * 16 + quad * 4 + r;
                const int col = bn + wn * NI * 16 + ni * 16 + lr;
                if (PROJ) {
                    const float bb = (col < 256) ? bias[col]
                                   : (col < 512) ? bias2[col - 256]
                                                 : bias3[col - 512];
                    const float v = acc[mi][ni][r] + bb;
                    if (col < 256) Cb[(size_t)row * 256 + col] = f2bf(v);
                    else           Cb2[(size_t)row * 384 + (col - 256)] = f2bf(v);
                } else {
                    float v = acc[mi][ni][r] + bias[col];
                    if (RES) { if (row < M) v += R[(size_t)row * N + col]; }
                    if (RELU) v = fmaxf(v, 0.0f);
                    if (F32OUT) Cf[(size_t)row * N + col] = v;
                    if (BF16OUT) Cb[(size_t)row * N + col] = f2bf(v);
                }
            }
        }
    }
}

// ---------------------------------------------------------------------------
// Fused GEMM(N=256) + bias + residual + LayerNorm. Tile 64 rows x 256 cols;
// wave w owns all 64 rows x cols [w*64,+64) (MI=4, NI=4). BK = NC*32.
// LN: shfl_xor over lr -> LDS [row][8] -> reduce. Grid = M_PAD/64.
// ---------------------------------------------------------------------------
template<bool HASB, int NC>
__global__ __launch_bounds__(256)
void mgemm_ln(const unsigned short* __restrict__ A,
              const unsigned short* __restrict__ BT,
              const float* __restrict__ bias,
              const float* __restrict__ R,
              const float* __restrict__ g,
              const float* __restrict__ beta,
              float* __restrict__ outF,
              unsigned short* __restrict__ outB,
              int M, int K)
{
    __shared__ __align__(16) unsigned short smemA[NC * 64 * 32];    // NC*4 KB
    __shared__ __align__(16) unsigned short smemB[NC * 256 * 32];   // NC*16 KB
    const int lane = threadIdx.x & 63;
    const int w    = threadIdx.x >> 6;
    const int lr   = lane & 15, quad = lane >> 4;
    const int bm   = blockIdx.x * 64;
    const int srow = lane >> 2;
    const int selt = (lane & 3) << 3;

    floatx4 acc[4][4];
    #pragma unroll
    for (int i = 0; i < 4; ++i)
        #pragma unroll
        for (int j = 0; j < 4; ++j)
            acc[i][j] = (floatx4){0.f, 0.f, 0.f, 0.f};

    for (int k0 = 0; k0 < K; k0 += NC * 32) {
        #pragma unroll
        for (int c = 0; c < NC; ++c) {
            const unsigned short* ga = A + (size_t)(bm + w * 16 + srow) * K + k0 + c * 32 + selt;
            __builtin_amdgcn_global_load_lds(AS1C(ga), AS3(smemA + c * 2048 + w * 512), 16, 0, 0);
            #pragma unroll
            for (int jj = 0; jj < 4; ++jj) {
                const int j = 4 * w + jj;
                const unsigned short* gb = BT + (size_t)(j * 16 + srow) * K + k0 + c * 32 + selt;
                __builtin_amdgcn_global_load_lds(AS1C(gb), AS3(smemB + c * 8192 + j * 512), 16, 0, 0);
            }
        }
        __syncthreads();
        #pragma unroll
        for (int c = 0; c < NC; ++c) {
            short8 av[4], bv[4];
            #pragma unroll
            for (int mi = 0; mi < 4; ++mi)
                av[mi] = *(const short8*)&smemA[c * 2048 + (mi * 16 + lr) * 32 + quad * 8];
            #pragma unroll
            for (int ni = 0; ni < 4; ++ni)
                bv[ni] = *(const short8*)&smemB[c * 8192 + (w * 64 + ni * 16 + lr) * 32 + quad * 8];
            #pragma unroll
            for (int mi = 0; mi < 4; ++mi)
                #pragma unroll
                for (int ni = 0; ni < 4; ++ni)
                    acc[mi][ni] = __builtin_amdgcn_mfma_f32_16x16x32_bf16(
                        av[mi], bv[ni], acc[mi][ni], 0, 0, 0);
        }
        __syncthreads();
    }

    float bs[4], gs[4], bts[4];
    #pragma unroll
    for (int ni = 0; ni < 4; ++ni) {
        const int col = w * 64 + ni * 16 + lr;
        bs[ni] = bias[col]; gs[ni] = g[col]; bts[ni] = beta[col];
    }
    float* lnbuf = (float*)smemA;   // 64 rows x 8 floats = 2 KB (reuse)

    #pragma unroll
    for (int mi = 0; mi < 4; ++mi) {
        #pragma unroll
        for (int r = 0; r < 4; ++r) {
            const int rl = mi * 16 + quad * 4 + r;
            const int grow = bm + rl;
            const bool act = grow < M;
            float p = 0.f, q = 0.f;
            #pragma unroll
            for (int ni = 0; ni < 4; ++ni) {
                const int col = w * 64 + ni * 16 + lr;
                const float rv = act ? R[(size_t)grow * 256 + col] : 0.f;
                const float x = acc[mi][ni][r] + bs[ni] + rv;
                acc[mi][ni][r] = x;
                p += x; q += x * x;
            }
            #pragma unroll
            for (int o = 1; o < 16; o <<= 1) {
                p += __shfl_xor(p, o, 64);
                q += __shfl_xor(q, o, 64);
            }
            if (lr == 0) {
                lnbuf[rl * 8 + 2 * w]     = p;
                lnbuf[rl * 8 + 2 * w + 1] = q;
            }
        }
    }
    __syncthreads();
    #pragma unroll
    for (int mi = 0; mi < 4; ++mi) {
        #pragma unroll
        for (int r = 0; r < 4; ++r) {
            const int rl = mi * 16 + quad * 4 + r;
            const int grow = bm + rl;
            const float4 pa = *(const float4*)&lnbuf[rl * 8];
            const float4 pb = *(const float4*)&lnbuf[rl * 8 + 4];
            const float s  = pa.x + pa.z + pb.x + pb.z;
            const float s2 = pa.y + pa.w + pb.y + pb.w;
            const float mean = s * (1.0f / 256.0f);
            const float var  = s2 * (1.0f / 256.0f) - mean * mean;
            const float rs   = rsqrtf(var + 1e-5f);
            if (grow < M) {
                #pragma unroll
                for (int ni = 0; ni < 4; ++ni) {
                    const int col = w * 64 + ni * 16 + lr;
                    const float y = (acc[mi][ni][r] - mean) * rs * gs[ni] + bts[ni];
                    outF[(size_t)grow * 256 + col] = y;
                    if (HASB) outB[(size_t)grow * 256 + col] = f2bf(y);
                }
            }
        }
    }
}

// ---------------------------------------------------------------------------
// fp32 [M,256] -> bf16 [M_PAD,256] with zero padding rows (layer 0 only)
// ---------------------------------------------------------------------------
__global__ __launch_bounds__(256)
void convpad(const float* __restrict__ X, unsigned short* __restrict__ Y, int M)
{
    const int idx = blockIdx.x * 256 + threadIdx.x;
    const int row = idx >> 6;
    const int c4  = (idx & 63) << 2;
    if (row >= M_PAD) return;
    float4 v = {0.f, 0.f, 0.f, 0.f};
    if (row < M) v = ((const float4*)(X + (size_t)row * 256))[c4 >> 2];
    unsigned p0 = (unsigned)f2bf(v.x) | ((unsigned)f2bf(v.y) << 16);
    unsigned p1 = (unsigned)f2bf(v.z) | ((unsigned)f2bf(v.w) << 16);
    uint2 o; o.x = p0; o.y = p1;
    *(uint2*)(Y + (size_t)row * 256 + c4) = o;
}

// ---------------------------------------------------------------------------
// Merged weight transpose+convert (12 segments, one dispatch).
// ---------------------------------------------------------------------------
struct WJobs {
    const float* W[12];
    unsigned short* WT[12];
    int K[12], N[12], tx[12], start[12];
};

__global__ __launch_bounds__(256)
void wtrans_all(WJobs jb)
{
    __shared__ float t[32][33];
    const int bx = blockIdx.x;
    int seg = 0;
    #pragma unroll
    for (int s = 1; s < 12; ++s) if (bx >= jb.start[s]) seg = s;
    const float* W = jb.W[seg];
    unsigned short* WT = jb.WT[seg];
    const int K = jb.K[seg], N = jb.N[seg], tx = jb.tx[seg];
    const int local = bx - jb.start[seg];
    const int n0 = (local % tx) * 32, k0 = (local / tx) * 32;
    const int c = threadIdx.x & 31, r0 = threadIdx.x >> 5;
    #pragma unroll
    for (int rr = r0; rr < 32; rr += 8)
        t[rr][c] = W[(size_t)(k0 + rr) * N + n0 + c];
    __syncthreads();
    #pragma unroll
    for (int rr = r0; rr < 32; rr += 8)
        WT[(size_t)(n0 + rr) * K + k0 + c] = f2bf(t[c][rr]);
}

// ---------------------------------------------------------------------------
// MSDA, 2-phase (round-8 version: bf16 off/attn, division-free, __expf,
// packed float2 fma).
// ---------------------------------------------------------------------------
__global__ __launch_bounds__(256)
void msda_kernel(const unsigned short* __restrict__ valb,
                 const unsigned short* __restrict__ oab,   // [M,384] bf16
                 const float* __restrict__ vr,
                 unsigned short* __restrict__ out)
{
    __shared__ __align__(16) char smeta[8 * 128 * 32];
    const int t = threadIdx.x;

    {
        const int wv = t >> 6, lane = t & 63;
        const int lqA = wv * 2 + (lane >> 5);
        const int bq = blockIdx.x * 8 + lqA;
        const int h = (lane >> 2) & 7;
        const int j = lane & 3;
        if (bq < M_TOT) {
            const int b = (bq >= S_TOT) ? 1 : 0;
            const int q = bq - b * S_TOT;
            const int bofs = b * (S_TOT * 512);
            int Hq, rr, cc, lq;
            if (q < 10000)      { lq = 0; Hq = 100; rr = q / 100;              cc = q - rr * 100; }
            else if (q < 12500) { lq = 1; Hq = 50;  int r2 = q - 10000; rr = r2 / 50; cc = r2 - rr * 50; }
            else if (q < 13125) { lq = 2; Hq = 25;  int r2 = q - 12500; rr = r2 / 25; cc = r2 - rr * 25; }
            else                { lq = 3; Hq = 13;  int r2 = q - 13125; rr = r2 / 13; cc = r2 - rr * 13; }
            const float rxb = (cc + 0.5f) / (vr[(b * 4 + lq) * 2 + 0] * (float)Hq);
            const float ryb = (rr + 0.5f) / (vr[(b * 4 + lq) * 2 + 1] * (float)Hq);
            const int HWt[4] = {100, 50, 25, 13};
            const int stt[4] = {0, 10000, 12500, 13125};
            const int HW = HWt[j], st = stt[j];
            const float fW = (float)HW;
            const float refxw = rxb * vr[(b * 4 + j) * 2 + 0] * fW - 0.5f;
            const float refyw = ryb * vr[(b * 4 + j) * 2 + 1] * fW - 0.5f;
            const unsigned short* row = oab + (size_t)bq * 384;
            const uint2 lgu = *(const uint2*)(row + 256 + h * 16 + j * 4);
            const float l0 = bflo(lgu.x), l1 = bfhi(lgu.x);
            const float l2 = bflo(lgu.y), l3 = bfhi(lgu.y);
            float mx = fmaxf(fmaxf(l0, l1), fmaxf(l2, l3));
            mx = fmaxf(mx, __shfl_xor(mx, 1, 64));
            mx = fmaxf(mx, __shfl_xor(mx, 2, 64));
            const float e0 = __expf(l0 - mx), e1 = __expf(l1 - mx);
            const float e2 = __expf(l2 - mx), e3 = __expf(l3 - mx);
            float ss = e0 + e1 + e2 + e3;
            ss += __shfl_xor(ss, 1, 64);
            ss += __shfl_xor(ss, 2, 64);
            const float inv = 1.0f / ss;
            const uint4 ou = *(const uint4*)(row + h * 32 + j * 8);
            const float oxs[4] = {bflo(ou.x), bflo(ou.y), bflo(ou.z), bflo(ou.w)};
            const float oys[4] = {bfhi(ou.x), bfhi(ou.y), bfhi(ou.z), bfhi(ou.w)};
            const float aw[4]  = {e0 * inv, e1 * inv, e2 * inv, e3 * inv};
            char* mb = smeta + (size_t)(lqA * 128 + h * 16 + j * 4) * 32;
            const int swz = ((h * 4 + j) & 7) << 4;
            #pragma unroll
            for (int p = 0; p < 4; ++p) {
                const float x = refxw + oxs[p];
                const float y = refyw + oys[p];
                const float x0f = floorf(x), y0f = floorf(y);
                const int x0 = (int)x0f, y0 = (int)y0f;
                const float fx = x - x0f, fy = y - y0f;
                const float wb[4] = {(1.f - fx) * (1.f - fy), fx * (1.f - fy),
                                     (1.f - fx) * fy,         fx * fy};
                const int xs[2] = {x0, x0 + 1};
                const int ys2[2] = {y0, y0 + 1};
                int iv[4]; float wv4[4];
                #pragma unroll
                for (int k = 0; k < 4; ++k) {
                    const int xi = xs[k & 1], yi = ys2[k >> 1];
                    const bool vld = ((unsigned)xi < (unsigned)HW) && ((unsigned)yi < (unsigned)HW);
                    const int xc = min(max(xi, 0), HW - 1);
                    const int yc = min(max(yi, 0), HW - 1);
                    iv[k] = bofs + ((st + yc * HW + xc) << 9) + (h << 6);
                    wv4[k] = vld ? wb[k] * aw[p] : 0.0f;
                }
                int4 i4; i4.x = iv[0]; i4.y = iv[1]; i4.z = iv[2]; i4.w = iv[3];
                float4 w4; w4.x = wv4[0]; w4.y = wv4[1]; w4.z = wv4[2]; w4.w = wv4[3];
                *(int4*)(mb + ((p * 32) ^ swz)) = i4;
                *(float4*)(mb + ((p * 32 + 16) ^ swz)) = w4;
            }
        }
    }
    __syncthreads();
    {
        const int lq2 = t >> 5;
        const int r = t & 31;
        const int h2 = r >> 2;
        const int cg = r & 3;
        const int bq2 = blockIdx.x * 8 + lq2;
        if (bq2 < M_TOT) {
            const char* vbase = (const char*)valb;
            const unsigned cgo = cg * 16;
            floatx2 a0 = {0.f, 0.f}, a1 = {0.f, 0.f}, a2 = {0.f, 0.f}, a3 = {0.f, 0.f};
            const char* mb2 = smeta + (size_t)(lq2 * 128 + h2 * 16) * 32;
            #pragma unroll 4
            for (int s = 0; s < 16; ++s) {
                const int swz2 = ((h2 * 4 + (s >> 2)) & 7) << 4;
                const int4  iv = *(const int4*)(mb2 + ((s * 32) ^ swz2));
                const float4 w4 = *(const float4*)(mb2 + ((s * 32 + 16) ^ swz2));
                const uint4 u0 = *(const uint4*)(vbase + (unsigned)(iv.x + cgo));
                const uint4 u1 = *(const uint4*)(vbase + (unsigned)(iv.y + cgo));
                const uint4 u2 = *(const uint4*)(vbase + (unsigned)(iv.z + cgo));
                const uint4 u3 = *(const uint4*)(vbase + (unsigned)(iv.w + cgo));
                #define ACC8(UU, WW) { \
                    const floatx2 w2 = {WW, WW}; \
                    const floatx2 t0 = {bflo(UU.x), bfhi(UU.x)}; \
                    const floatx2 t1 = {bflo(UU.y), bfhi(UU.y)}; \
                    const floatx2 t2 = {bflo(UU.z), bfhi(UU.z)}; \
                    const floatx2 t3 = {bflo(UU.w), bfhi(UU.w)}; \
                    a0 += w2 * t0; a1 += w2 * t1; a2 += w2 * t2; a3 += w2 * t3; }
                ACC8(u0, w4.x) ACC8(u1, w4.y) ACC8(u2, w4.z) ACC8(u3, w4.w)
                #undef ACC8
            }
            uint4 o;
            o.x = (unsigned)f2bf(a0.x) | ((unsigned)f2bf(a0.y) << 16);
            o.y = (unsigned)f2bf(a1.x) | ((unsigned)f2bf(a1.y) << 16);
            o.z = (unsigned)f2bf(a2.x) | ((unsigned)f2bf(a2.y) << 16);
            o.w = (unsigned)f2bf(a3.x) | ((unsigned)f2bf(a3.y) << 16);
            *(uint4*)(out + (size_t)bq2 * 256 + h2 * 32 + cg * 8) = o;
        }
    }
}

// ---------------------------------------------------------------------------
// Host-side orchestration
// ---------------------------------------------------------------------------
extern "C" void kernel_launch(void* const* d_in, const int* in_sizes, int n_in,
                              void* d_out, int out_size, void* d_ws, size_t ws_size,
                              hipStream_t stream)
{
    const float* src    = (const float*)d_in[0];
    const float* vr     = (const float*)d_in[2];
    const float* W_off  = (const float*)d_in[3];
    const float* b_off  = (const float*)d_in[4];
    const float* W_attn = (const float*)d_in[5];
    const float* b_attn = (const float*)d_in[6];
    const float* W_val  = (const float*)d_in[7];
    const float* b_val  = (const float*)d_in[8];
    const float* W_out  = (const float*)d_in[9];
    const float* b_out  = (const float*)d_in[10];
    const float* ln1_g  = (const float*)d_in[11];
    const float* ln1_b  = (const float*)d_in[12];
    const float* W1     = (const float*)d_in[13];
    const float* b1     = (const float*)d_in[14];
    const float* W2     = (const float*)d_in[15];
    const float* b2     = (const float*)d_in[16];
    const float* ln2_g  = (const float*)d_in[17];
    const float* ln2_b  = (const float*)d_in[18];
    float* out = (float*)d_out;

    const int M = M_TOT;

    // --- workspace (bytes), total 112,066,560 ---
    // [0,          54,525,952)  HBF bf16 [M_PAD,1024]; overlays:
    //     OAB  bf16 [M_PAD,384] at [0, 20,447,232)
    //     VALB bf16 [M_PAD,256] at [20,447,232, 34,078,720)
    // [54,525,952, 81,788,928)  T1  f32 [M_PAD,256]
    // [81,788,928, 95,420,416)  RB  bf16 [M_PAD,256]
    // [95,420,416,109,051,904)  YBF bf16 [M_PAD,256]
    // [109,051,904,112,066,560) WT  transposed weights
    char* wsb = (char*)d_ws;
    unsigned short* HBF  = (unsigned short*)wsb;
    unsigned short* OAB  = (unsigned short*)wsb;
    unsigned short* VALB = (unsigned short*)(wsb + 20447232);
    float*          T1   = (float*)(wsb + 54525952);
    unsigned short* RB   = (unsigned short*)(wsb + 81788928);
    unsigned short* YBF  = (unsigned short*)(wsb + 95420416);
    unsigned short* WT   = (unsigned short*)(wsb + 109051904);

    const size_t LWT = 753664;
    const size_t oProj = 0, oOut = 163840, oW1 = 229376, oW2 = 491520;

    WJobs jb;
    int startAcc = 0;
    for (int i = 0; i < 2; ++i) {
        unsigned short* wt = WT + i * LWT;
        const float* srcs[6] = {W_val + i * 65536, W_off + i * 65536, W_attn + i * 32768,
                                W_out + i * 65536, W1 + i * 262144, W2 + i * 262144};
        unsigned short* dsts[6] = {wt + oProj, wt + oProj + 65536, wt + oProj + 131072,
                                   wt + oOut, wt + oW1, wt + oW2};
        const int Ks[6] = {256, 256, 256, 256, 256, 1024};
        const int Ns[6] = {256, 256, 128, 256, 1024, 256};
        for (int s = 0; s < 6; ++s) {
            const int idx = i * 6 + s;
            jb.W[idx] = srcs[s]; jb.WT[idx] = dsts[s];
            jb.K[idx] = Ks[s]; jb.N[idx] = Ns[s]; jb.tx[idx] = Ns[s] / 32;
            jb.start[idx] = startAcc;
            startAcc += (Ns[s] / 32) * (Ks[s] / 32);
        }
    }
    wtrans_all<<<dim3(startAcc), 256, 0, stream>>>(jb);

    const int GM128 = M_PAD / 128;  // 208
    const int GM64  = M_PAD / 64;   // 416
    const dim3 blk(256);

    for (int i = 0; i < 2; ++i) {
        const float* xin = (i == 0) ? src : out;
        unsigned short* wt = WT + i * LWT;

        if (i == 0)
            convpad<<<dim3(M_PAD / 4), blk, 0, stream>>>(src, RB, M);

        // merged projections: N=640 -> VALB (bf16) + OAB (bf16), BK=128
        mgemm<64, 4, false, false, false, false, true><<<dim3(5, GM64), blk, 0, stream>>>(
            RB, wt + oProj, b_val + i * 256, b_off + i * 256, b_attn + i * 128,
            nullptr, nullptr, VALB, OAB, M, 640, 256);

        // deformable sampling
        msda_kernel<<<dim3((M + 7) / 8), blk, 0, stream>>>(VALB, OAB, vr, YBF);

        // fused out-proj + residual(xin) + LN1 -> T1 (f32) + RB (bf16), BK=128
        mgemm_ln<true, 4><<<dim3(GM64), blk, 0, stream>>>(
            YBF, wt + oOut, b_out + i * 256, xin,
            ln1_g + i * 256, ln1_b + i * 256, T1, RB, M, 256);

        // FFN1 (relu, bf16 hidden overlays OAB+VALB region), BK=64
        mgemm<128, 2, true, false, false, true, false><<<dim3(8, GM128), blk, 0, stream>>>(
            RB, wt + oW1, b1 + i * 1024, nullptr, nullptr,
            nullptr, nullptr, HBF, nullptr, M, 1024, 256);

        // fused FFN2 + residual(T1) + LN2 -> out (f32) [+ RB bf16 on layer 0], BK=128
        if (i == 0)
            mgemm_ln<true, 4><<<dim3(GM64), blk, 0, stream>>>(
                HBF, wt + oW2, b2 + i * 256, T1,
                ln2_g + i * 256, ln2_b + i * 256, out, RB, M, 1024);
        else
            mgemm_ln<false, 4><<<dim3(GM64), blk, 0, stream>>>(
                HBF, wt + oW2, b2 + i * 256, T1,
                ln2_g + i * 256, ln2_b + i * 256, out, nullptr, M, 1024);
    }
}

// Round 10
// 451.988 us; speedup vs baseline: 1.1749x; 1.1749x over previous
//
#include <hip/hip_runtime.h>
#include <math.h>

// Deformable-DETR encoder, 2 layers. Round 10: mgemm_ln reverted to TM=64 /
// BK=64 (BK=128 occupancy cliff, cf. m132); all residuals carried in bf16 —
// the fp32 T1 round-trip is gone (LN outputs written bf16-only except the
// final layer-1 LN2 -> d_out).

#define S_TOT 13294
#define BATCH 2
#define M_TOT (BATCH * S_TOT)     // 26588
#define M_PAD 26624               // 208*128 = 416*64

typedef __attribute__((ext_vector_type(8))) short short8;
typedef __attribute__((ext_vector_type(4))) float floatx4;
typedef __attribute__((ext_vector_type(2))) float floatx2;

#define AS1C(p) ((const __attribute__((address_space(1))) void*)(p))
#define AS3(p)  ((__attribute__((address_space(3))) void*)(p))

static __device__ __forceinline__ unsigned short f2bf(float x) {
    union { float f; unsigned u; } v; v.f = x;
    unsigned r = v.u + 0x7FFFu + ((v.u >> 16) & 1u);
    return (unsigned short)(r >> 16);
}
static __device__ __forceinline__ float b2f(unsigned short u) {
    union { unsigned u; float f; } v; v.u = (unsigned)u << 16; return v.f;
}
static __device__ __forceinline__ float bflo(unsigned u) {
    union { unsigned u; float f; } v; v.u = u << 16; return v.f;
}
static __device__ __forceinline__ float bfhi(unsigned u) {
    union { unsigned u; float f; } v; v.u = u & 0xFFFF0000u; return v.f;
}

// ---------------------------------------------------------------------------
// bf16 MFMA GEMM, BK=64. TM=128: 4 waves 2x2 of 64x64. TM=64: 4 waves 64x32.
// PROJ epilogue: col<256 -> bf16 Cb[.,256]; col>=256 -> bf16 Cb2[.,384].
// ---------------------------------------------------------------------------
template<int TM, bool RELU, bool BF16OUT, bool PROJ>
__global__ __launch_bounds__(256)
void mgemm(const unsigned short* __restrict__ A,
           const unsigned short* __restrict__ BT,
           const float* __restrict__ bias,
           const float* __restrict__ bias2,
           const float* __restrict__ bias3,
           unsigned short* __restrict__ Cb,
           unsigned short* __restrict__ Cb2,
           int M, int N, int K)
{
    constexpr int WM = (TM == 128) ? 2 : 1;
    constexpr int WN = 4 / WM;
    constexpr int MI = TM / (WM * 16);
    constexpr int NI = 128 / (WN * 16);
    __shared__ __align__(16) unsigned short smemA[2 * TM * 32];
    __shared__ __align__(16) unsigned short smemB[2 * 128 * 32];
    const int tid  = threadIdx.x;
    const int lane = tid & 63;
    const int w    = tid >> 6;
    const int wm   = w % WM, wn = w / WM;
    const int lr   = lane & 15, quad = lane >> 4;
    const int bm   = blockIdx.y * TM;
    const int bn   = blockIdx.x * 128;

    floatx4 acc[MI][NI];
    #pragma unroll
    for (int i = 0; i < MI; ++i)
        #pragma unroll
        for (int j = 0; j < NI; ++j)
            acc[i][j] = (floatx4){0.f, 0.f, 0.f, 0.f};

    const int srow = lane >> 2;
    const int selt = (lane & 3) << 3;

    for (int k0 = 0; k0 < K; k0 += 64) {
        #pragma unroll
        for (int c = 0; c < 2; ++c) {
            if (TM == 128) {
                #pragma unroll
                for (int jj = 0; jj < 2; ++jj) {
                    const int j = 2 * w + jj;
                    const unsigned short* ga = A  + (size_t)(bm + j * 16 + srow) * K + k0 + c * 32 + selt;
                    const unsigned short* gb = BT + (size_t)(bn + j * 16 + srow) * K + k0 + c * 32 + selt;
                    __builtin_amdgcn_global_load_lds(AS1C(ga), AS3(smemA + c * (TM * 32) + j * 512), 16, 0, 0);
                    __builtin_amdgcn_global_load_lds(AS1C(gb), AS3(smemB + c * 4096 + j * 512), 16, 0, 0);
                }
            } else {
                const unsigned short* ga = A + (size_t)(bm + w * 16 + srow) * K + k0 + c * 32 + selt;
                __builtin_amdgcn_global_load_lds(AS1C(ga), AS3(smemA + c * (TM * 32) + w * 512), 16, 0, 0);
                #pragma unroll
                for (int jj = 0; jj < 2; ++jj) {
                    const int j = 2 * w + jj;
                    const unsigned short* gb = BT + (size_t)(bn + j * 16 + srow) * K + k0 + c * 32 + selt;
                    __builtin_amdgcn_global_load_lds(AS1C(gb), AS3(smemB + c * 4096 + j * 512), 16, 0, 0);
                }
            }
        }
        __syncthreads();

        #pragma unroll
        for (int c = 0; c < 2; ++c) {
            short8 av[MI], bv[NI];
            #pragma unroll
            for (int mi = 0; mi < MI; ++mi)
                av[mi] = *(const short8*)&smemA[c * (TM * 32) + (wm * MI * 16 + mi * 16 + lr) * 32 + quad * 8];
            #pragma unroll
            for (int ni = 0; ni < NI; ++ni)
                bv[ni] = *(const short8*)&smemB[c * 4096 + (wn * NI * 16 + ni * 16 + lr) * 32 + quad * 8];
            #pragma unroll
            for (int mi = 0; mi < MI; ++mi)
                #pragma unroll
                for (int ni = 0; ni < NI; ++ni)
                    acc[mi][ni] = __builtin_amdgcn_mfma_f32_16x16x32_bf16(
                        av[mi], bv[ni], acc[mi][ni], 0, 0, 0);
        }
        __syncthreads();
    }

    #pragma unroll
    for (int mi = 0; mi < MI; ++mi) {
        #pragma unroll
        for (int ni = 0; ni < NI; ++ni) {
            #pragma unroll
            for (int r = 0; r < 4; ++r) {
                const int row = bm + wm * MI * 16 + mi * 16 + quad * 4 + r;
                const int col = bn + wn * NI * 16 + ni * 16 + lr;
                if (PROJ) {
                    const float bb = (col < 256) ? bias[col]
                                   : (col < 512) ? bias2[col - 256]
                                                 : bias3[col - 512];
                    const float v = acc[mi][ni][r] + bb;
                    if (col < 256) Cb[(size_t)row * 256 + col] = f2bf(v);
                    else           Cb2[(size_t)row * 384 + (col - 256)] = f2bf(v);
                } else {
                    float v = acc[mi][ni][r] + bias[col];
                    if (RELU) v = fmaxf(v, 0.0f);
                    if (BF16OUT) Cb[(size_t)row * N + col] = f2bf(v);
                }
            }
        }
    }
}

// ---------------------------------------------------------------------------
// Fused GEMM(N=256) + bias + bf16 residual + LayerNorm. Tile 64 rows x 256
// cols; wave w owns all 64 rows x cols [w*64,+64) (MI=4, NI=4). BK=64.
// Outputs: optional f32 outF, optional bf16 outB (in-place over R is safe:
// each thread reads its own residual element before any write).
// ---------------------------------------------------------------------------
template<bool HASF, bool HASB>
__global__ __launch_bounds__(256)
void mgemm_ln(const unsigned short* __restrict__ A,
              const unsigned short* __restrict__ BT,
              const float* __restrict__ bias,
              const unsigned short* __restrict__ R,   // bf16 residual [*,256]
              const float* __restrict__ g,
              const float* __restrict__ beta,
              float* __restrict__ outF,
              unsigned short* __restrict__ outB,
              int M, int K)
{
    __shared__ __align__(16) unsigned short smemA[2 * 64 * 32];    // 8 KB
    __shared__ __align__(16) unsigned short smemB[2 * 256 * 32];   // 32 KB
    const int lane = threadIdx.x & 63;
    const int w    = threadIdx.x >> 6;
    const int lr   = lane & 15, quad = lane >> 4;
    const int bm   = blockIdx.x * 64;
    const int srow = lane >> 2;
    const int selt = (lane & 3) << 3;

    floatx4 acc[4][4];
    #pragma unroll
    for (int i = 0; i < 4; ++i)
        #pragma unroll
        for (int j = 0; j < 4; ++j)
            acc[i][j] = (floatx4){0.f, 0.f, 0.f, 0.f};

    for (int k0 = 0; k0 < K; k0 += 64) {
        #pragma unroll
        for (int c = 0; c < 2; ++c) {
            const unsigned short* ga = A + (size_t)(bm + w * 16 + srow) * K + k0 + c * 32 + selt;
            __builtin_amdgcn_global_load_lds(AS1C(ga), AS3(smemA + c * 2048 + w * 512), 16, 0, 0);
            #pragma unroll
            for (int jj = 0; jj < 4; ++jj) {
                const int j = 4 * w + jj;
                const unsigned short* gb = BT + (size_t)(j * 16 + srow) * K + k0 + c * 32 + selt;
                __builtin_amdgcn_global_load_lds(AS1C(gb), AS3(smemB + c * 8192 + j * 512), 16, 0, 0);
            }
        }
        __syncthreads();
        #pragma unroll
        for (int c = 0; c < 2; ++c) {
            short8 av[4], bv[4];
            #pragma unroll
            for (int mi = 0; mi < 4; ++mi)
                av[mi] = *(const short8*)&smemA[c * 2048 + (mi * 16 + lr) * 32 + quad * 8];
            #pragma unroll
            for (int ni = 0; ni < 4; ++ni)
                bv[ni] = *(const short8*)&smemB[c * 8192 + (w * 64 + ni * 16 + lr) * 32 + quad * 8];
            #pragma unroll
            for (int mi = 0; mi < 4; ++mi)
                #pragma unroll
                for (int ni = 0; ni < 4; ++ni)
                    acc[mi][ni] = __builtin_amdgcn_mfma_f32_16x16x32_bf16(
                        av[mi], bv[ni], acc[mi][ni], 0, 0, 0);
        }
        __syncthreads();
    }

    float bs[4], gs[4], bts[4];
    #pragma unroll
    for (int ni = 0; ni < 4; ++ni) {
        const int col = w * 64 + ni * 16 + lr;
        bs[ni] = bias[col]; gs[ni] = g[col]; bts[ni] = beta[col];
    }
    float* lnbuf = (float*)smemA;   // 64 rows x 8 floats = 2 KB (reuse)

    #pragma unroll
    for (int mi = 0; mi < 4; ++mi) {
        #pragma unroll
        for (int r = 0; r < 4; ++r) {
            const int rl = mi * 16 + quad * 4 + r;
            const int grow = bm + rl;
            const bool act = grow < M;
            float p = 0.f, q = 0.f;
            #pragma unroll
            for (int ni = 0; ni < 4; ++ni) {
                const int col = w * 64 + ni * 16 + lr;
                const float rv = act ? b2f(R[(size_t)grow * 256 + col]) : 0.f;
                const float x = acc[mi][ni][r] + bs[ni] + rv;
                acc[mi][ni][r] = x;
                p += x; q += x * x;
            }
            #pragma unroll
            for (int o = 1; o < 16; o <<= 1) {
                p += __shfl_xor(p, o, 64);
                q += __shfl_xor(q, o, 64);
            }
            if (lr == 0) {
                lnbuf[rl * 8 + 2 * w]     = p;
                lnbuf[rl * 8 + 2 * w + 1] = q;
            }
        }
    }
    __syncthreads();
    #pragma unroll
    for (int mi = 0; mi < 4; ++mi) {
        #pragma unroll
        for (int r = 0; r < 4; ++r) {
            const int rl = mi * 16 + quad * 4 + r;
            const int grow = bm + rl;
            const float4 pa = *(const float4*)&lnbuf[rl * 8];
            const float4 pb = *(const float4*)&lnbuf[rl * 8 + 4];
            const float s  = pa.x + pa.z + pb.x + pb.z;
            const float s2 = pa.y + pa.w + pb.y + pb.w;
            const float mean = s * (1.0f / 256.0f);
            const float var  = s2 * (1.0f / 256.0f) - mean * mean;
            const float rs   = rsqrtf(var + 1e-5f);
            if (grow < M) {
                #pragma unroll
                for (int ni = 0; ni < 4; ++ni) {
                    const int col = w * 64 + ni * 16 + lr;
                    const float y = (acc[mi][ni][r] - mean) * rs * gs[ni] + bts[ni];
                    if (HASF) outF[(size_t)grow * 256 + col] = y;
                    if (HASB) outB[(size_t)grow * 256 + col] = f2bf(y);
                }
            }
        }
    }
}

// ---------------------------------------------------------------------------
// fp32 [M,256] -> bf16 [M_PAD,256] with zero padding rows (layer 0 only)
// ---------------------------------------------------------------------------
__global__ __launch_bounds__(256)
void convpad(const float* __restrict__ X, unsigned short* __restrict__ Y, int M)
{
    const int idx = blockIdx.x * 256 + threadIdx.x;
    const int row = idx >> 6;
    const int c4  = (idx & 63) << 2;
    if (row >= M_PAD) return;
    float4 v = {0.f, 0.f, 0.f, 0.f};
    if (row < M) v = ((const float4*)(X + (size_t)row * 256))[c4 >> 2];
    unsigned p0 = (unsigned)f2bf(v.x) | ((unsigned)f2bf(v.y) << 16);
    unsigned p1 = (unsigned)f2bf(v.z) | ((unsigned)f2bf(v.w) << 16);
    uint2 o; o.x = p0; o.y = p1;
    *(uint2*)(Y + (size_t)row * 256 + c4) = o;
}

// ---------------------------------------------------------------------------
// Merged weight transpose+convert (12 segments, one dispatch).
// ---------------------------------------------------------------------------
struct WJobs {
    const float* W[12];
    unsigned short* WT[12];
    int K[12], N[12], tx[12], start[12];
};

__global__ __launch_bounds__(256)
void wtrans_all(WJobs jb)
{
    __shared__ float t[32][33];
    const int bx = blockIdx.x;
    int seg = 0;
    #pragma unroll
    for (int s = 1; s < 12; ++s) if (bx >= jb.start[s]) seg = s;
    const float* W = jb.W[seg];
    unsigned short* WT = jb.WT[seg];
    const int K = jb.K[seg], N = jb.N[seg], tx = jb.tx[seg];
    const int local = bx - jb.start[seg];
    const int n0 = (local % tx) * 32, k0 = (local / tx) * 32;
    const int c = threadIdx.x & 31, r0 = threadIdx.x >> 5;
    #pragma unroll
    for (int rr = r0; rr < 32; rr += 8)
        t[rr][c] = W[(size_t)(k0 + rr) * N + n0 + c];
    __syncthreads();
    #pragma unroll
    for (int rr = r0; rr < 32; rr += 8)
        WT[(size_t)(n0 + rr) * K + k0 + c] = f2bf(t[c][rr]);
}

// ---------------------------------------------------------------------------
// MSDA, 2-phase (round-8 version: bf16 off/attn, division-free, __expf,
// packed float2 fma).
// ---------------------------------------------------------------------------
__global__ __launch_bounds__(256)
void msda_kernel(const unsigned short* __restrict__ valb,
                 const unsigned short* __restrict__ oab,   // [M,384] bf16
                 const float* __restrict__ vr,
                 unsigned short* __restrict__ out)
{
    __shared__ __align__(16) char smeta[8 * 128 * 32];
    const int t = threadIdx.x;

    {
        const int wv = t >> 6, lane = t & 63;
        const int lqA = wv * 2 + (lane >> 5);
        const int bq = blockIdx.x * 8 + lqA;
        const int h = (lane >> 2) & 7;
        const int j = lane & 3;
        if (bq < M_TOT) {
            const int b = (bq >= S_TOT) ? 1 : 0;
            const int q = bq - b * S_TOT;
            const int bofs = b * (S_TOT * 512);
            int Hq, rr, cc, lq;
            if (q < 10000)      { lq = 0; Hq = 100; rr = q / 100;              cc = q - rr * 100; }
            else if (q < 12500) { lq = 1; Hq = 50;  int r2 = q - 10000; rr = r2 / 50; cc = r2 - rr * 50; }
            else if (q < 13125) { lq = 2; Hq = 25;  int r2 = q - 12500; rr = r2 / 25; cc = r2 - rr * 25; }
            else                { lq = 3; Hq = 13;  int r2 = q - 13125; rr = r2 / 13; cc = r2 - rr * 13; }
            const float rxb = (cc + 0.5f) / (vr[(b * 4 + lq) * 2 + 0] * (float)Hq);
            const float ryb = (rr + 0.5f) / (vr[(b * 4 + lq) * 2 + 1] * (float)Hq);
            const int HWt[4] = {100, 50, 25, 13};
            const int stt[4] = {0, 10000, 12500, 13125};
            const int HW = HWt[j], st = stt[j];
            const float fW = (float)HW;
            const float refxw = rxb * vr[(b * 4 + j) * 2 + 0] * fW - 0.5f;
            const float refyw = ryb * vr[(b * 4 + j) * 2 + 1] * fW - 0.5f;
            const unsigned short* row = oab + (size_t)bq * 384;
            const uint2 lgu = *(const uint2*)(row + 256 + h * 16 + j * 4);
            const float l0 = bflo(lgu.x), l1 = bfhi(lgu.x);
            const float l2 = bflo(lgu.y), l3 = bfhi(lgu.y);
            float mx = fmaxf(fmaxf(l0, l1), fmaxf(l2, l3));
            mx = fmaxf(mx, __shfl_xor(mx, 1, 64));
            mx = fmaxf(mx, __shfl_xor(mx, 2, 64));
            const float e0 = __expf(l0 - mx), e1 = __expf(l1 - mx);
            const float e2 = __expf(l2 - mx), e3 = __expf(l3 - mx);
            float ss = e0 + e1 + e2 + e3;
            ss += __shfl_xor(ss, 1, 64);
            ss += __shfl_xor(ss, 2, 64);
            const float inv = 1.0f / ss;
            const uint4 ou = *(const uint4*)(row + h * 32 + j * 8);
            const float oxs[4] = {bflo(ou.x), bflo(ou.y), bflo(ou.z), bflo(ou.w)};
            const float oys[4] = {bfhi(ou.x), bfhi(ou.y), bfhi(ou.z), bfhi(ou.w)};
            const float aw[4]  = {e0 * inv, e1 * inv, e2 * inv, e3 * inv};
            char* mb = smeta + (size_t)(lqA * 128 + h * 16 + j * 4) * 32;
            const int swz = ((h * 4 + j) & 7) << 4;
            #pragma unroll
            for (int p = 0; p < 4; ++p) {
                const float x = refxw + oxs[p];
                const float y = refyw + oys[p];
                const float x0f = floorf(x), y0f = floorf(y);
                const int x0 = (int)x0f, y0 = (int)y0f;
                const float fx = x - x0f, fy = y - y0f;
                const float wb[4] = {(1.f - fx) * (1.f - fy), fx * (1.f - fy),
                                     (1.f - fx) * fy,         fx * fy};
                const int xs[2] = {x0, x0 + 1};
                const int ys2[2] = {y0, y0 + 1};
                int iv[4]; float wv4[4];
                #pragma unroll
                for (int k = 0; k < 4; ++k) {
                    const int xi = xs[k & 1], yi = ys2[k >> 1];
                    const bool vld = ((unsigned)xi < (unsigned)HW) && ((unsigned)yi < (unsigned)HW);
                    const int xc = min(max(xi, 0), HW - 1);
                    const int yc = min(max(yi, 0), HW - 1);
                    iv[k] = bofs + ((st + yc * HW + xc) << 9) + (h << 6);
                    wv4[k] = vld ? wb[k] * aw[p] : 0.0f;
                }
                int4 i4; i4.x = iv[0]; i4.y = iv[1]; i4.z = iv[2]; i4.w = iv[3];
                float4 w4; w4.x = wv4[0]; w4.y = wv4[1]; w4.z = wv4[2]; w4.w = wv4[3];
                *(int4*)(mb + ((p * 32) ^ swz)) = i4;
                *(float4*)(mb + ((p * 32 + 16) ^ swz)) = w4;
            }
        }
    }
    __syncthreads();
    {
        const int lq2 = t >> 5;
        const int r = t & 31;
        const int h2 = r >> 2;
        const int cg = r & 3;
        const int bq2 = blockIdx.x * 8 + lq2;
        if (bq2 < M_TOT) {
            const char* vbase = (const char*)valb;
            const unsigned cgo = cg * 16;
            floatx2 a0 = {0.f, 0.f}, a1 = {0.f, 0.f}, a2 = {0.f, 0.f}, a3 = {0.f, 0.f};
            const char* mb2 = smeta + (size_t)(lq2 * 128 + h2 * 16) * 32;
            #pragma unroll 4
            for (int s = 0; s < 16; ++s) {
                const int swz2 = ((h2 * 4 + (s >> 2)) & 7) << 4;
                const int4  iv = *(const int4*)(mb2 + ((s * 32) ^ swz2));
                const float4 w4 = *(const float4*)(mb2 + ((s * 32 + 16) ^ swz2));
                const uint4 u0 = *(const uint4*)(vbase + (unsigned)(iv.x + cgo));
                const uint4 u1 = *(const uint4*)(vbase + (unsigned)(iv.y + cgo));
                const uint4 u2 = *(const uint4*)(vbase + (unsigned)(iv.z + cgo));
                const uint4 u3 = *(const uint4*)(vbase + (unsigned)(iv.w + cgo));
                #define ACC8(UU, WW) { \
                    const floatx2 w2 = {WW, WW}; \
                    const floatx2 t0 = {bflo(UU.x), bfhi(UU.x)}; \
                    const floatx2 t1 = {bflo(UU.y), bfhi(UU.y)}; \
                    const floatx2 t2 = {bflo(UU.z), bfhi(UU.z)}; \
                    const floatx2 t3 = {bflo(UU.w), bfhi(UU.w)}; \
                    a0 += w2 * t0; a1 += w2 * t1; a2 += w2 * t2; a3 += w2 * t3; }
                ACC8(u0, w4.x) ACC8(u1, w4.y) ACC8(u2, w4.z) ACC8(u3, w4.w)
                #undef ACC8
            }
            uint4 o;
            o.x = (unsigned)f2bf(a0.x) | ((unsigned)f2bf(a0.y) << 16);
            o.y = (unsigned)f2bf(a1.x) | ((unsigned)f2bf(a1.y) << 16);
            o.z = (unsigned)f2bf(a2.x) | ((unsigned)f2bf(a2.y) << 16);
            o.w = (unsigned)f2bf(a3.x) | ((unsigned)f2bf(a3.y) << 16);
            *(uint4*)(out + (size_t)bq2 * 256 + h2 * 32 + cg * 8) = o;
        }
    }
}

// ---------------------------------------------------------------------------
// Host-side orchestration
// ---------------------------------------------------------------------------
extern "C" void kernel_launch(void* const* d_in, const int* in_sizes, int n_in,
                              void* d_out, int out_size, void* d_ws, size_t ws_size,
                              hipStream_t stream)
{
    const float* src    = (const float*)d_in[0];
    const float* vr     = (const float*)d_in[2];
    const float* W_off  = (const float*)d_in[3];
    const float* b_off  = (const float*)d_in[4];
    const float* W_attn = (const float*)d_in[5];
    const float* b_attn = (const float*)d_in[6];
    const float* W_val  = (const float*)d_in[7];
    const float* b_val  = (const float*)d_in[8];
    const float* W_out  = (const float*)d_in[9];
    const float* b_out  = (const float*)d_in[10];
    const float* ln1_g  = (const float*)d_in[11];
    const float* ln1_b  = (const float*)d_in[12];
    const float* W1     = (const float*)d_in[13];
    const float* b1     = (const float*)d_in[14];
    const float* W2     = (const float*)d_in[15];
    const float* b2     = (const float*)d_in[16];
    const float* ln2_g  = (const float*)d_in[17];
    const float* ln2_b  = (const float*)d_in[18];
    float* out = (float*)d_out;

    const int M = M_TOT;

    // --- workspace (bytes), total 112,066,560 ---
    // [0,          54,525,952)  HBF bf16 [M_PAD,1024]; overlays:
    //     OAB  bf16 [M_PAD,384] at [0, 20,447,232)
    //     VALB bf16 [M_PAD,256] at [20,447,232, 34,078,720)
    // [54,525,952, 68,157,440)  X1B bf16 [M_PAD,256]  (post-LN1, bf16)
    // [81,788,928, 95,420,416)  RB  bf16 [M_PAD,256]  (x input, bf16)
    // [95,420,416,109,051,904)  YBF bf16 [M_PAD,256]  (msda out)
    // [109,051,904,112,066,560) WT  transposed weights
    char* wsb = (char*)d_ws;
    unsigned short* HBF  = (unsigned short*)wsb;
    unsigned short* OAB  = (unsigned short*)wsb;
    unsigned short* VALB = (unsigned short*)(wsb + 20447232);
    unsigned short* X1B  = (unsigned short*)(wsb + 54525952);
    unsigned short* RB   = (unsigned short*)(wsb + 81788928);
    unsigned short* YBF  = (unsigned short*)(wsb + 95420416);
    unsigned short* WT   = (unsigned short*)(wsb + 109051904);

    const size_t LWT = 753664;
    const size_t oProj = 0, oOut = 163840, oW1 = 229376, oW2 = 491520;

    WJobs jb;
    int startAcc = 0;
    for (int i = 0; i < 2; ++i) {
        unsigned short* wt = WT + i * LWT;
        const float* srcs[6] = {W_val + i * 65536, W_off + i * 65536, W_attn + i * 32768,
                                W_out + i * 65536, W1 + i * 262144, W2 + i * 262144};
        unsigned short* dsts[6] = {wt + oProj, wt + oProj + 65536, wt + oProj + 131072,
                                   wt + oOut, wt + oW1, wt + oW2};
        const int Ks[6] = {256, 256, 256, 256, 256, 1024};
        const int Ns[6] = {256, 256, 128, 256, 1024, 256};
        for (int s = 0; s < 6; ++s) {
            const int idx = i * 6 + s;
            jb.W[idx] = srcs[s]; jb.WT[idx] = dsts[s];
            jb.K[idx] = Ks[s]; jb.N[idx] = Ns[s]; jb.tx[idx] = Ns[s] / 32;
            jb.start[idx] = startAcc;
            startAcc += (Ns[s] / 32) * (Ks[s] / 32);
        }
    }
    wtrans_all<<<dim3(startAcc), 256, 0, stream>>>(jb);

    const int GM128 = M_PAD / 128;  // 208
    const int GM64  = M_PAD / 64;   // 416
    const dim3 blk(256);

    for (int i = 0; i < 2; ++i) {
        unsigned short* wt = WT + i * LWT;

        if (i == 0)
            convpad<<<dim3(M_PAD / 4), blk, 0, stream>>>(src, RB, M);

        // merged projections: N=640 -> VALB (bf16) + OAB (bf16)
        mgemm<64, false, false, true><<<dim3(5, GM64), blk, 0, stream>>>(
            RB, wt + oProj, b_val + i * 256, b_off + i * 256, b_attn + i * 128,
            VALB, OAB, M, 640, 256);

        // deformable sampling
        msda_kernel<<<dim3((M + 7) / 8), blk, 0, stream>>>(VALB, OAB, vr, YBF);

        // fused out-proj + residual(RB bf16) + LN1 -> X1B (bf16 only)
        mgemm_ln<false, true><<<dim3(GM64), blk, 0, stream>>>(
            YBF, wt + oOut, b_out + i * 256, RB,
            ln1_g + i * 256, ln1_b + i * 256, nullptr, X1B, M, 256);

        // FFN1 (relu, bf16 hidden overlays OAB+VALB region)
        mgemm<128, true, true, false><<<dim3(8, GM128), blk, 0, stream>>>(
            X1B, wt + oW1, b1 + i * 1024, nullptr, nullptr,
            HBF, nullptr, M, 1024, 256);

        // fused FFN2 + residual(X1B bf16) + LN2:
        //   layer 0 -> RB (bf16, next layer's x); layer 1 -> out (f32)
        if (i == 0)
            mgemm_ln<false, true><<<dim3(GM64), blk, 0, stream>>>(
                HBF, wt + oW2, b2 + i * 256, X1B,
                ln2_g + i * 256, ln2_b + i * 256, nullptr, RB, M, 1024);
        else
            mgemm_ln<true, false><<<dim3(GM64), blk, 0, stream>>>(
                HBF, wt + oW2, b2 + i * 256, X1B,
                ln2_g + i * 256, ln2_b + i * 256, out, nullptr, M, 1024);
    }
}

// Round 11
// 444.660 us; speedup vs baseline: 1.1943x; 1.0165x over previous
//
#include <hip/hip_runtime.h>
#include <math.h>

// Deformable-DETR encoder, 2 layers. Round 11: double-buffered mgemm_ln
// (one barrier per K-tile; loads for tile k+1 issued before MFMA of tile k,
// so the vmcnt(0) barrier drain lands after a tile of compute). 80 KB LDS,
// 2 blocks/CU — grid (1.6/CU) was already the occupancy binder.

#define S_TOT 13294
#define BATCH 2
#define M_TOT (BATCH * S_TOT)     // 26588
#define M_PAD 26624               // 208*128 = 416*64

typedef __attribute__((ext_vector_type(8))) short short8;
typedef __attribute__((ext_vector_type(4))) float floatx4;
typedef __attribute__((ext_vector_type(2))) float floatx2;

#define AS1C(p) ((const __attribute__((address_space(1))) void*)(p))
#define AS3(p)  ((__attribute__((address_space(3))) void*)(p))

static __device__ __forceinline__ unsigned short f2bf(float x) {
    union { float f; unsigned u; } v; v.f = x;
    unsigned r = v.u + 0x7FFFu + ((v.u >> 16) & 1u);
    return (unsigned short)(r >> 16);
}
static __device__ __forceinline__ float b2f(unsigned short u) {
    union { unsigned u; float f; } v; v.u = (unsigned)u << 16; return v.f;
}
static __device__ __forceinline__ float bflo(unsigned u) {
    union { unsigned u; float f; } v; v.u = u << 16; return v.f;
}
static __device__ __forceinline__ float bfhi(unsigned u) {
    union { unsigned u; float f; } v; v.u = u & 0xFFFF0000u; return v.f;
}

// ---------------------------------------------------------------------------
// bf16 MFMA GEMM, BK=64, single-buffered (healthy-occupancy shapes).
// TM=128: 4 waves 2x2 of 64x64. TM=64: 4 waves 64x32.
// PROJ epilogue: col<256 -> bf16 Cb[.,256]; col>=256 -> bf16 Cb2[.,384].
// ---------------------------------------------------------------------------
template<int TM, bool RELU, bool BF16OUT, bool PROJ>
__global__ __launch_bounds__(256)
void mgemm(const unsigned short* __restrict__ A,
           const unsigned short* __restrict__ BT,
           const float* __restrict__ bias,
           const float* __restrict__ bias2,
           const float* __restrict__ bias3,
           unsigned short* __restrict__ Cb,
           unsigned short* __restrict__ Cb2,
           int M, int N, int K)
{
    constexpr int WM = (TM == 128) ? 2 : 1;
    constexpr int WN = 4 / WM;
    constexpr int MI = TM / (WM * 16);
    constexpr int NI = 128 / (WN * 16);
    __shared__ __align__(16) unsigned short smemA[2 * TM * 32];
    __shared__ __align__(16) unsigned short smemB[2 * 128 * 32];
    const int tid  = threadIdx.x;
    const int lane = tid & 63;
    const int w    = tid >> 6;
    const int wm   = w % WM, wn = w / WM;
    const int lr   = lane & 15, quad = lane >> 4;
    const int bm   = blockIdx.y * TM;
    const int bn   = blockIdx.x * 128;

    floatx4 acc[MI][NI];
    #pragma unroll
    for (int i = 0; i < MI; ++i)
        #pragma unroll
        for (int j = 0; j < NI; ++j)
            acc[i][j] = (floatx4){0.f, 0.f, 0.f, 0.f};

    const int srow = lane >> 2;
    const int selt = (lane & 3) << 3;

    for (int k0 = 0; k0 < K; k0 += 64) {
        #pragma unroll
        for (int c = 0; c < 2; ++c) {
            if (TM == 128) {
                #pragma unroll
                for (int jj = 0; jj < 2; ++jj) {
                    const int j = 2 * w + jj;
                    const unsigned short* ga = A  + (size_t)(bm + j * 16 + srow) * K + k0 + c * 32 + selt;
                    const unsigned short* gb = BT + (size_t)(bn + j * 16 + srow) * K + k0 + c * 32 + selt;
                    __builtin_amdgcn_global_load_lds(AS1C(ga), AS3(smemA + c * (TM * 32) + j * 512), 16, 0, 0);
                    __builtin_amdgcn_global_load_lds(AS1C(gb), AS3(smemB + c * 4096 + j * 512), 16, 0, 0);
                }
            } else {
                const unsigned short* ga = A + (size_t)(bm + w * 16 + srow) * K + k0 + c * 32 + selt;
                __builtin_amdgcn_global_load_lds(AS1C(ga), AS3(smemA + c * (TM * 32) + w * 512), 16, 0, 0);
                #pragma unroll
                for (int jj = 0; jj < 2; ++jj) {
                    const int j = 2 * w + jj;
                    const unsigned short* gb = BT + (size_t)(bn + j * 16 + srow) * K + k0 + c * 32 + selt;
                    __builtin_amdgcn_global_load_lds(AS1C(gb), AS3(smemB + c * 4096 + j * 512), 16, 0, 0);
                }
            }
        }
        __syncthreads();

        #pragma unroll
        for (int c = 0; c < 2; ++c) {
            short8 av[MI], bv[NI];
            #pragma unroll
            for (int mi = 0; mi < MI; ++mi)
                av[mi] = *(const short8*)&smemA[c * (TM * 32) + (wm * MI * 16 + mi * 16 + lr) * 32 + quad * 8];
            #pragma unroll
            for (int ni = 0; ni < NI; ++ni)
                bv[ni] = *(const short8*)&smemB[c * 4096 + (wn * NI * 16 + ni * 16 + lr) * 32 + quad * 8];
            #pragma unroll
            for (int mi = 0; mi < MI; ++mi)
                #pragma unroll
                for (int ni = 0; ni < NI; ++ni)
                    acc[mi][ni] = __builtin_amdgcn_mfma_f32_16x16x32_bf16(
                        av[mi], bv[ni], acc[mi][ni], 0, 0, 0);
        }
        __syncthreads();
    }

    #pragma unroll
    for (int mi = 0; mi < MI; ++mi) {
        #pragma unroll
        for (int ni = 0; ni < NI; ++ni) {
            #pragma unroll
            for (int r = 0; r < 4; ++r) {
                const int row = bm + wm * MI * 16 + mi * 16 + quad * 4 + r;
                const int col = bn + wn * NI * 16 + ni * 16 + lr;
                if (PROJ) {
                    const float bb = (col < 256) ? bias[col]
                                   : (col < 512) ? bias2[col - 256]
                                                 : bias3[col - 512];
                    const float v = acc[mi][ni][r] + bb;
                    if (col < 256) Cb[(size_t)row * 256 + col] = f2bf(v);
                    else           Cb2[(size_t)row * 384 + (col - 256)] = f2bf(v);
                } else {
                    float v = acc[mi][ni][r] + bias[col];
                    if (RELU) v = fmaxf(v, 0.0f);
                    if (BF16OUT) Cb[(size_t)row * N + col] = f2bf(v);
                }
            }
        }
    }
}

// ---------------------------------------------------------------------------
// Fused GEMM(N=256) + bias + bf16 residual + LayerNorm. DOUBLE-BUFFERED:
// one barrier per K-tile; loads of tile k+1 issue right after the barrier,
// overlapping the MFMA of tile k. Tile 64 rows x 256 cols; wave w owns all
// 64 rows x cols [w*64,+64). LDS: A 2x8 KB + B 2x32 KB = 80 KB.
// ---------------------------------------------------------------------------
template<bool HASF, bool HASB>
__global__ __launch_bounds__(256)
void mgemm_ln(const unsigned short* __restrict__ A,
              const unsigned short* __restrict__ BT,
              const float* __restrict__ bias,
              const unsigned short* __restrict__ R,   // bf16 residual [*,256]
              const float* __restrict__ g,
              const float* __restrict__ beta,
              float* __restrict__ outF,
              unsigned short* __restrict__ outB,
              int M, int K)
{
    __shared__ __align__(16) unsigned short smemA[2 * 4096];    // 2 bufs x 8 KB
    __shared__ __align__(16) unsigned short smemB[2 * 16384];   // 2 bufs x 32 KB
    const int lane = threadIdx.x & 63;
    const int w    = threadIdx.x >> 6;
    const int lr   = lane & 15, quad = lane >> 4;
    const int bm   = blockIdx.x * 64;
    const int srow = lane >> 2;
    const int selt = (lane & 3) << 3;

    floatx4 acc[4][4];
    #pragma unroll
    for (int i = 0; i < 4; ++i)
        #pragma unroll
        for (int j = 0; j < 4; ++j)
            acc[i][j] = (floatx4){0.f, 0.f, 0.f, 0.f};

    auto stage = [&](int kt, int buf) {
        const int k0 = kt * 64;
        #pragma unroll
        for (int c = 0; c < 2; ++c) {
            const unsigned short* ga = A + (size_t)(bm + w * 16 + srow) * K + k0 + c * 32 + selt;
            __builtin_amdgcn_global_load_lds(AS1C(ga), AS3(smemA + buf * 4096 + c * 2048 + w * 512), 16, 0, 0);
            #pragma unroll
            for (int jj = 0; jj < 4; ++jj) {
                const int j = 4 * w + jj;
                const unsigned short* gb = BT + (size_t)(j * 16 + srow) * K + k0 + c * 32 + selt;
                __builtin_amdgcn_global_load_lds(AS1C(gb), AS3(smemB + buf * 16384 + c * 8192 + j * 512), 16, 0, 0);
            }
        }
    };

    const int NK = K >> 6;
    stage(0, 0);
    for (int kt = 0; kt < NK; ++kt) {
        const int buf = kt & 1;
        __syncthreads();                    // drains loads for buf (issued last iter)
        if (kt + 1 < NK) stage(kt + 1, buf ^ 1);
        #pragma unroll
        for (int c = 0; c < 2; ++c) {
            short8 av[4], bv[4];
            #pragma unroll
            for (int mi = 0; mi < 4; ++mi)
                av[mi] = *(const short8*)&smemA[buf * 4096 + c * 2048 + (mi * 16 + lr) * 32 + quad * 8];
            #pragma unroll
            for (int ni = 0; ni < 4; ++ni)
                bv[ni] = *(const short8*)&smemB[buf * 16384 + c * 8192 + (w * 64 + ni * 16 + lr) * 32 + quad * 8];
            #pragma unroll
            for (int mi = 0; mi < 4; ++mi)
                #pragma unroll
                for (int ni = 0; ni < 4; ++ni)
                    acc[mi][ni] = __builtin_amdgcn_mfma_f32_16x16x32_bf16(
                        av[mi], bv[ni], acc[mi][ni], 0, 0, 0);
        }
    }

    float bs[4], gs[4], bts[4];
    #pragma unroll
    for (int ni = 0; ni < 4; ++ni) {
        const int col = w * 64 + ni * 16 + lr;
        bs[ni] = bias[col]; gs[ni] = g[col]; bts[ni] = beta[col];
    }
    // NK is even (4 or 16): last MFMA tile read buf 1, so buf 0's smemA is
    // free for the LN scratch without an extra barrier.
    float* lnbuf = (float*)smemA;   // 64 rows x 8 floats = 2 KB

    #pragma unroll
    for (int mi = 0; mi < 4; ++mi) {
        #pragma unroll
        for (int r = 0; r < 4; ++r) {
            const int rl = mi * 16 + quad * 4 + r;
            const int grow = bm + rl;
            const bool act = grow < M;
            float p = 0.f, q = 0.f;
            #pragma unroll
            for (int ni = 0; ni < 4; ++ni) {
                const int col = w * 64 + ni * 16 + lr;
                const float rv = act ? b2f(R[(size_t)grow * 256 + col]) : 0.f;
                const float x = acc[mi][ni][r] + bs[ni] + rv;
                acc[mi][ni][r] = x;
                p += x; q += x * x;
            }
            #pragma unroll
            for (int o = 1; o < 16; o <<= 1) {
                p += __shfl_xor(p, o, 64);
                q += __shfl_xor(q, o, 64);
            }
            if (lr == 0) {
                lnbuf[rl * 8 + 2 * w]     = p;
                lnbuf[rl * 8 + 2 * w + 1] = q;
            }
        }
    }
    __syncthreads();
    #pragma unroll
    for (int mi = 0; mi < 4; ++mi) {
        #pragma unroll
        for (int r = 0; r < 4; ++r) {
            const int rl = mi * 16 + quad * 4 + r;
            const int grow = bm + rl;
            const float4 pa = *(const float4*)&lnbuf[rl * 8];
            const float4 pb = *(const float4*)&lnbuf[rl * 8 + 4];
            const float s  = pa.x + pa.z + pb.x + pb.z;
            const float s2 = pa.y + pa.w + pb.y + pb.w;
            const float mean = s * (1.0f / 256.0f);
            const float var  = s2 * (1.0f / 256.0f) - mean * mean;
            const float rs   = rsqrtf(var + 1e-5f);
            if (grow < M) {
                #pragma unroll
                for (int ni = 0; ni < 4; ++ni) {
                    const int col = w * 64 + ni * 16 + lr;
                    const float y = (acc[mi][ni][r] - mean) * rs * gs[ni] + bts[ni];
                    if (HASF) outF[(size_t)grow * 256 + col] = y;
                    if (HASB) outB[(size_t)grow * 256 + col] = f2bf(y);
                }
            }
        }
    }
}

// ---------------------------------------------------------------------------
// fp32 [M,256] -> bf16 [M_PAD,256] with zero padding rows (layer 0 only)
// ---------------------------------------------------------------------------
__global__ __launch_bounds__(256)
void convpad(const float* __restrict__ X, unsigned short* __restrict__ Y, int M)
{
    const int idx = blockIdx.x * 256 + threadIdx.x;
    const int row = idx >> 6;
    const int c4  = (idx & 63) << 2;
    if (row >= M_PAD) return;
    float4 v = {0.f, 0.f, 0.f, 0.f};
    if (row < M) v = ((const float4*)(X + (size_t)row * 256))[c4 >> 2];
    unsigned p0 = (unsigned)f2bf(v.x) | ((unsigned)f2bf(v.y) << 16);
    unsigned p1 = (unsigned)f2bf(v.z) | ((unsigned)f2bf(v.w) << 16);
    uint2 o; o.x = p0; o.y = p1;
    *(uint2*)(Y + (size_t)row * 256 + c4) = o;
}

// ---------------------------------------------------------------------------
// Merged weight transpose+convert (12 segments, one dispatch).
// ---------------------------------------------------------------------------
struct WJobs {
    const float* W[12];
    unsigned short* WT[12];
    int K[12], N[12], tx[12], start[12];
};

__global__ __launch_bounds__(256)
void wtrans_all(WJobs jb)
{
    __shared__ float t[32][33];
    const int bx = blockIdx.x;
    int seg = 0;
    #pragma unroll
    for (int s = 1; s < 12; ++s) if (bx >= jb.start[s]) seg = s;
    const float* W = jb.W[seg];
    unsigned short* WT = jb.WT[seg];
    const int K = jb.K[seg], N = jb.N[seg], tx = jb.tx[seg];
    const int local = bx - jb.start[seg];
    const int n0 = (local % tx) * 32, k0 = (local / tx) * 32;
    const int c = threadIdx.x & 31, r0 = threadIdx.x >> 5;
    #pragma unroll
    for (int rr = r0; rr < 32; rr += 8)
        t[rr][c] = W[(size_t)(k0 + rr) * N + n0 + c];
    __syncthreads();
    #pragma unroll
    for (int rr = r0; rr < 32; rr += 8)
        WT[(size_t)(n0 + rr) * K + k0 + c] = f2bf(t[c][rr]);
}

// ---------------------------------------------------------------------------
// MSDA, 2-phase (bf16 off/attn, division-free, __expf, packed float2 fma).
// ---------------------------------------------------------------------------
__global__ __launch_bounds__(256)
void msda_kernel(const unsigned short* __restrict__ valb,
                 const unsigned short* __restrict__ oab,   // [M,384] bf16
                 const float* __restrict__ vr,
                 unsigned short* __restrict__ out)
{
    __shared__ __align__(16) char smeta[8 * 128 * 32];
    const int t = threadIdx.x;

    {
        const int wv = t >> 6, lane = t & 63;
        const int lqA = wv * 2 + (lane >> 5);
        const int bq = blockIdx.x * 8 + lqA;
        const int h = (lane >> 2) & 7;
        const int j = lane & 3;
        if (bq < M_TOT) {
            const int b = (bq >= S_TOT) ? 1 : 0;
            const int q = bq - b * S_TOT;
            const int bofs = b * (S_TOT * 512);
            int Hq, rr, cc, lq;
            if (q < 10000)      { lq = 0; Hq = 100; rr = q / 100;              cc = q - rr * 100; }
            else if (q < 12500) { lq = 1; Hq = 50;  int r2 = q - 10000; rr = r2 / 50; cc = r2 - rr * 50; }
            else if (q < 13125) { lq = 2; Hq = 25;  int r2 = q - 12500; rr = r2 / 25; cc = r2 - rr * 25; }
            else                { lq = 3; Hq = 13;  int r2 = q - 13125; rr = r2 / 13; cc = r2 - rr * 13; }
            const float rxb = (cc + 0.5f) / (vr[(b * 4 + lq) * 2 + 0] * (float)Hq);
            const float ryb = (rr + 0.5f) / (vr[(b * 4 + lq) * 2 + 1] * (float)Hq);
            const int HWt[4] = {100, 50, 25, 13};
            const int stt[4] = {0, 10000, 12500, 13125};
            const int HW = HWt[j], st = stt[j];
            const float fW = (float)HW;
            const float refxw = rxb * vr[(b * 4 + j) * 2 + 0] * fW - 0.5f;
            const float refyw = ryb * vr[(b * 4 + j) * 2 + 1] * fW - 0.5f;
            const unsigned short* row = oab + (size_t)bq * 384;
            const uint2 lgu = *(const uint2*)(row + 256 + h * 16 + j * 4);
            const float l0 = bflo(lgu.x), l1 = bfhi(lgu.x);
            const float l2 = bflo(lgu.y), l3 = bfhi(lgu.y);
            float mx = fmaxf(fmaxf(l0, l1), fmaxf(l2, l3));
            mx = fmaxf(mx, __shfl_xor(mx, 1, 64));
            mx = fmaxf(mx, __shfl_xor(mx, 2, 64));
            const float e0 = __expf(l0 - mx), e1 = __expf(l1 - mx);
            const float e2 = __expf(l2 - mx), e3 = __expf(l3 - mx);
            float ss = e0 + e1 + e2 + e3;
            ss += __shfl_xor(ss, 1, 64);
            ss += __shfl_xor(ss, 2, 64);
            const float inv = 1.0f / ss;
            const uint4 ou = *(const uint4*)(row + h * 32 + j * 8);
            const float oxs[4] = {bflo(ou.x), bflo(ou.y), bflo(ou.z), bflo(ou.w)};
            const float oys[4] = {bfhi(ou.x), bfhi(ou.y), bfhi(ou.z), bfhi(ou.w)};
            const float aw[4]  = {e0 * inv, e1 * inv, e2 * inv, e3 * inv};
            char* mb = smeta + (size_t)(lqA * 128 + h * 16 + j * 4) * 32;
            const int swz = ((h * 4 + j) & 7) << 4;
            #pragma unroll
            for (int p = 0; p < 4; ++p) {
                const float x = refxw + oxs[p];
                const float y = refyw + oys[p];
                const float x0f = floorf(x), y0f = floorf(y);
                const int x0 = (int)x0f, y0 = (int)y0f;
                const float fx = x - x0f, fy = y - y0f;
                const float wb[4] = {(1.f - fx) * (1.f - fy), fx * (1.f - fy),
                                     (1.f - fx) * fy,         fx * fy};
                const int xs[2] = {x0, x0 + 1};
                const int ys2[2] = {y0, y0 + 1};
                int iv[4]; float wv4[4];
                #pragma unroll
                for (int k = 0; k < 4; ++k) {
                    const int xi = xs[k & 1], yi = ys2[k >> 1];
                    const bool vld = ((unsigned)xi < (unsigned)HW) && ((unsigned)yi < (unsigned)HW);
                    const int xc = min(max(xi, 0), HW - 1);
                    const int yc = min(max(yi, 0), HW - 1);
                    iv[k] = bofs + ((st + yc * HW + xc) << 9) + (h << 6);
                    wv4[k] = vld ? wb[k] * aw[p] : 0.0f;
                }
                int4 i4; i4.x = iv[0]; i4.y = iv[1]; i4.z = iv[2]; i4.w = iv[3];
                float4 w4; w4.x = wv4[0]; w4.y = wv4[1]; w4.z = wv4[2]; w4.w = wv4[3];
                *(int4*)(mb + ((p * 32) ^ swz)) = i4;
                *(float4*)(mb + ((p * 32 + 16) ^ swz)) = w4;
            }
        }
    }
    __syncthreads();
    {
        const int lq2 = t >> 5;
        const int r = t & 31;
        const int h2 = r >> 2;
        const int cg = r & 3;
        const int bq2 = blockIdx.x * 8 + lq2;
        if (bq2 < M_TOT) {
            const char* vbase = (const char*)valb;
            const unsigned cgo = cg * 16;
            floatx2 a0 = {0.f, 0.f}, a1 = {0.f, 0.f}, a2 = {0.f, 0.f}, a3 = {0.f, 0.f};
            const char* mb2 = smeta + (size_t)(lq2 * 128 + h2 * 16) * 32;
            #pragma unroll 4
            for (int s = 0; s < 16; ++s) {
                const int swz2 = ((h2 * 4 + (s >> 2)) & 7) << 4;
                const int4  iv = *(const int4*)(mb2 + ((s * 32) ^ swz2));
                const float4 w4 = *(const float4*)(mb2 + ((s * 32 + 16) ^ swz2));
                const uint4 u0 = *(const uint4*)(vbase + (unsigned)(iv.x + cgo));
                const uint4 u1 = *(const uint4*)(vbase + (unsigned)(iv.y + cgo));
                const uint4 u2 = *(const uint4*)(vbase + (unsigned)(iv.z + cgo));
                const uint4 u3 = *(const uint4*)(vbase + (unsigned)(iv.w + cgo));
                #define ACC8(UU, WW) { \
                    const floatx2 w2 = {WW, WW}; \
                    const floatx2 t0 = {bflo(UU.x), bfhi(UU.x)}; \
                    const floatx2 t1 = {bflo(UU.y), bfhi(UU.y)}; \
                    const floatx2 t2 = {bflo(UU.z), bfhi(UU.z)}; \
                    const floatx2 t3 = {bflo(UU.w), bfhi(UU.w)}; \
                    a0 += w2 * t0; a1 += w2 * t1; a2 += w2 * t2; a3 += w2 * t3; }
                ACC8(u0, w4.x) ACC8(u1, w4.y) ACC8(u2, w4.z) ACC8(u3, w4.w)
                #undef ACC8
            }
            uint4 o;
            o.x = (unsigned)f2bf(a0.x) | ((unsigned)f2bf(a0.y) << 16);
            o.y = (unsigned)f2bf(a1.x) | ((unsigned)f2bf(a1.y) << 16);
            o.z = (unsigned)f2bf(a2.x) | ((unsigned)f2bf(a2.y) << 16);
            o.w = (unsigned)f2bf(a3.x) | ((unsigned)f2bf(a3.y) << 16);
            *(uint4*)(out + (size_t)bq2 * 256 + h2 * 32 + cg * 8) = o;
        }
    }
}

// ---------------------------------------------------------------------------
// Host-side orchestration
// ---------------------------------------------------------------------------
extern "C" void kernel_launch(void* const* d_in, const int* in_sizes, int n_in,
                              void* d_out, int out_size, void* d_ws, size_t ws_size,
                              hipStream_t stream)
{
    const float* src    = (const float*)d_in[0];
    const float* vr     = (const float*)d_in[2];
    const float* W_off  = (const float*)d_in[3];
    const float* b_off  = (const float*)d_in[4];
    const float* W_attn = (const float*)d_in[5];
    const float* b_attn = (const float*)d_in[6];
    const float* W_val  = (const float*)d_in[7];
    const float* b_val  = (const float*)d_in[8];
    const float* W_out  = (const float*)d_in[9];
    const float* b_out  = (const float*)d_in[10];
    const float* ln1_g  = (const float*)d_in[11];
    const float* ln1_b  = (const float*)d_in[12];
    const float* W1     = (const float*)d_in[13];
    const float* b1     = (const float*)d_in[14];
    const float* W2     = (const float*)d_in[15];
    const float* b2     = (const float*)d_in[16];
    const float* ln2_g  = (const float*)d_in[17];
    const float* ln2_b  = (const float*)d_in[18];
    float* out = (float*)d_out;

    const int M = M_TOT;

    // --- workspace (bytes), total 112,066,560 ---
    // [0,          54,525,952)  HBF bf16 [M_PAD,1024]; overlays:
    //     OAB  bf16 [M_PAD,384] at [0, 20,447,232)
    //     VALB bf16 [M_PAD,256] at [20,447,232, 34,078,720)
    // [54,525,952, 68,157,440)  X1B bf16 [M_PAD,256]  (post-LN1, bf16)
    // [81,788,928, 95,420,416)  RB  bf16 [M_PAD,256]  (x input, bf16)
    // [95,420,416,109,051,904)  YBF bf16 [M_PAD,256]  (msda out)
    // [109,051,904,112,066,560) WT  transposed weights
    char* wsb = (char*)d_ws;
    unsigned short* HBF  = (unsigned short*)wsb;
    unsigned short* OAB  = (unsigned short*)wsb;
    unsigned short* VALB = (unsigned short*)(wsb + 20447232);
    unsigned short* X1B  = (unsigned short*)(wsb + 54525952);
    unsigned short* RB   = (unsigned short*)(wsb + 81788928);
    unsigned short* YBF  = (unsigned short*)(wsb + 95420416);
    unsigned short* WT   = (unsigned short*)(wsb + 109051904);

    const size_t LWT = 753664;
    const size_t oProj = 0, oOut = 163840, oW1 = 229376, oW2 = 491520;

    WJobs jb;
    int startAcc = 0;
    for (int i = 0; i < 2; ++i) {
        unsigned short* wt = WT + i * LWT;
        const float* srcs[6] = {W_val + i * 65536, W_off + i * 65536, W_attn + i * 32768,
                                W_out + i * 65536, W1 + i * 262144, W2 + i * 262144};
        unsigned short* dsts[6] = {wt + oProj, wt + oProj + 65536, wt + oProj + 131072,
                                   wt + oOut, wt + oW1, wt + oW2};
        const int Ks[6] = {256, 256, 256, 256, 256, 1024};
        const int Ns[6] = {256, 256, 128, 256, 1024, 256};
        for (int s = 0; s < 6; ++s) {
            const int idx = i * 6 + s;
            jb.W[idx] = srcs[s]; jb.WT[idx] = dsts[s];
            jb.K[idx] = Ks[s]; jb.N[idx] = Ns[s]; jb.tx[idx] = Ns[s] / 32;
            jb.start[idx] = startAcc;
            startAcc += (Ns[s] / 32) * (Ks[s] / 32);
        }
    }
    wtrans_all<<<dim3(startAcc), 256, 0, stream>>>(jb);

    const int GM128 = M_PAD / 128;  // 208
    const int GM64  = M_PAD / 64;   // 416
    const dim3 blk(256);

    for (int i = 0; i < 2; ++i) {
        unsigned short* wt = WT + i * LWT;

        if (i == 0)
            convpad<<<dim3(M_PAD / 4), blk, 0, stream>>>(src, RB, M);

        // merged projections: N=640 -> VALB (bf16) + OAB (bf16)
        mgemm<64, false, false, true><<<dim3(5, GM64), blk, 0, stream>>>(
            RB, wt + oProj, b_val + i * 256, b_off + i * 256, b_attn + i * 128,
            VALB, OAB, M, 640, 256);

        // deformable sampling
        msda_kernel<<<dim3((M + 7) / 8), blk, 0, stream>>>(VALB, OAB, vr, YBF);

        // fused out-proj + residual(RB bf16) + LN1 -> X1B (bf16 only)
        mgemm_ln<false, true><<<dim3(GM64), blk, 0, stream>>>(
            YBF, wt + oOut, b_out + i * 256, RB,
            ln1_g + i * 256, ln1_b + i * 256, nullptr, X1B, M, 256);

        // FFN1 (relu, bf16 hidden overlays OAB+VALB region)
        mgemm<128, true, true, false><<<dim3(8, GM128), blk, 0, stream>>>(
            X1B, wt + oW1, b1 + i * 1024, nullptr, nullptr,
            HBF, nullptr, M, 1024, 256);

        // fused FFN2 + residual(X1B bf16) + LN2:
        //   layer 0 -> RB (bf16, next layer's x); layer 1 -> out (f32)
        if (i == 0)
            mgemm_ln<false, true><<<dim3(GM64), blk, 0, stream>>>(
                HBF, wt + oW2, b2 + i * 256, X1B,
                ln2_g + i * 256, ln2_b + i * 256, nullptr, RB, M, 1024);
        else
            mgemm_ln<true, false><<<dim3(GM64), blk, 0, stream>>>(
                HBF, wt + oW2, b2 + i * 256, X1B,
                ln2_g + i * 256, ln2_b + i * 256, out, nullptr, M, 1024);
    }
}

// Round 12
// 425.179 us; speedup vs baseline: 1.2490x; 1.0458x over previous
//
#include <hip/hip_runtime.h>
#include <math.h>

// Deformable-DETR encoder, 2 layers. Round 12: msda phase-B unpack diet
// (raw-reinterpret hi-bf16, no AND mask) + XCD-aware block swizzle for
// value-gather L2 locality. GEMM structure unchanged from round 11.

#define S_TOT 13294
#define BATCH 2
#define M_TOT (BATCH * S_TOT)     // 26588
#define M_PAD 26624               // 208*128 = 416*64

typedef __attribute__((ext_vector_type(8))) short short8;
typedef __attribute__((ext_vector_type(4))) float floatx4;
typedef __attribute__((ext_vector_type(2))) float floatx2;

#define AS1C(p) ((const __attribute__((address_space(1))) void*)(p))
#define AS3(p)  ((__attribute__((address_space(3))) void*)(p))

static __device__ __forceinline__ unsigned short f2bf(float x) {
    union { float f; unsigned u; } v; v.f = x;
    unsigned r = v.u + 0x7FFFu + ((v.u >> 16) & 1u);
    return (unsigned short)(r >> 16);
}
static __device__ __forceinline__ float b2f(unsigned short u) {
    union { unsigned u; float f; } v; v.u = (unsigned)u << 16; return v.f;
}
static __device__ __forceinline__ float bflo(unsigned u) {
    union { unsigned u; float f; } v; v.u = u << 16; return v.f;
}
static __device__ __forceinline__ float bfhi(unsigned u) {
    union { unsigned u; float f; } v; v.u = u & 0xFFFF0000u; return v.f;
}
// hi bf16 with low-half mantissa garbage (<=2^-7 rel, below bf16 rounding
// scale for our magnitudes) — saves the AND.
static __device__ __forceinline__ float braw(unsigned u) {
    union { unsigned u; float f; } v; v.u = u; return v.f;
}

// ---------------------------------------------------------------------------
// bf16 MFMA GEMM, BK=64, single-buffered (healthy-occupancy shapes).
// TM=128: 4 waves 2x2 of 64x64. TM=64: 4 waves 64x32.
// PROJ epilogue: col<256 -> bf16 Cb[.,256]; col>=256 -> bf16 Cb2[.,384].
// ---------------------------------------------------------------------------
template<int TM, bool RELU, bool BF16OUT, bool PROJ>
__global__ __launch_bounds__(256)
void mgemm(const unsigned short* __restrict__ A,
           const unsigned short* __restrict__ BT,
           const float* __restrict__ bias,
           const float* __restrict__ bias2,
           const float* __restrict__ bias3,
           unsigned short* __restrict__ Cb,
           unsigned short* __restrict__ Cb2,
           int M, int N, int K)
{
    constexpr int WM = (TM == 128) ? 2 : 1;
    constexpr int WN = 4 / WM;
    constexpr int MI = TM / (WM * 16);
    constexpr int NI = 128 / (WN * 16);
    __shared__ __align__(16) unsigned short smemA[2 * TM * 32];
    __shared__ __align__(16) unsigned short smemB[2 * 128 * 32];
    const int tid  = threadIdx.x;
    const int lane = tid & 63;
    const int w    = tid >> 6;
    const int wm   = w % WM, wn = w / WM;
    const int lr   = lane & 15, quad = lane >> 4;
    const int bm   = blockIdx.y * TM;
    const int bn   = blockIdx.x * 128;

    floatx4 acc[MI][NI];
    #pragma unroll
    for (int i = 0; i < MI; ++i)
        #pragma unroll
        for (int j = 0; j < NI; ++j)
            acc[i][j] = (floatx4){0.f, 0.f, 0.f, 0.f};

    const int srow = lane >> 2;
    const int selt = (lane & 3) << 3;

    for (int k0 = 0; k0 < K; k0 += 64) {
        #pragma unroll
        for (int c = 0; c < 2; ++c) {
            if (TM == 128) {
                #pragma unroll
                for (int jj = 0; jj < 2; ++jj) {
                    const int j = 2 * w + jj;
                    const unsigned short* ga = A  + (size_t)(bm + j * 16 + srow) * K + k0 + c * 32 + selt;
                    const unsigned short* gb = BT + (size_t)(bn + j * 16 + srow) * K + k0 + c * 32 + selt;
                    __builtin_amdgcn_global_load_lds(AS1C(ga), AS3(smemA + c * (TM * 32) + j * 512), 16, 0, 0);
                    __builtin_amdgcn_global_load_lds(AS1C(gb), AS3(smemB + c * 4096 + j * 512), 16, 0, 0);
                }
            } else {
                const unsigned short* ga = A + (size_t)(bm + w * 16 + srow) * K + k0 + c * 32 + selt;
                __builtin_amdgcn_global_load_lds(AS1C(ga), AS3(smemA + c * (TM * 32) + w * 512), 16, 0, 0);
                #pragma unroll
                for (int jj = 0; jj < 2; ++jj) {
                    const int j = 2 * w + jj;
                    const unsigned short* gb = BT + (size_t)(bn + j * 16 + srow) * K + k0 + c * 32 + selt;
                    __builtin_amdgcn_global_load_lds(AS1C(gb), AS3(smemB + c * 4096 + j * 512), 16, 0, 0);
                }
            }
        }
        __syncthreads();

        #pragma unroll
        for (int c = 0; c < 2; ++c) {
            short8 av[MI], bv[NI];
            #pragma unroll
            for (int mi = 0; mi < MI; ++mi)
                av[mi] = *(const short8*)&smemA[c * (TM * 32) + (wm * MI * 16 + mi * 16 + lr) * 32 + quad * 8];
            #pragma unroll
            for (int ni = 0; ni < NI; ++ni)
                bv[ni] = *(const short8*)&smemB[c * 4096 + (wn * NI * 16 + ni * 16 + lr) * 32 + quad * 8];
            #pragma unroll
            for (int mi = 0; mi < MI; ++mi)
                #pragma unroll
                for (int ni = 0; ni < NI; ++ni)
                    acc[mi][ni] = __builtin_amdgcn_mfma_f32_16x16x32_bf16(
                        av[mi], bv[ni], acc[mi][ni], 0, 0, 0);
        }
        __syncthreads();
    }

    #pragma unroll
    for (int mi = 0; mi < MI; ++mi) {
        #pragma unroll
        for (int ni = 0; ni < NI; ++ni) {
            #pragma unroll
            for (int r = 0; r < 4; ++r) {
                const int row = bm + wm * MI * 16 + mi * 16 + quad * 4 + r;
                const int col = bn + wn * NI * 16 + ni * 16 + lr;
                if (PROJ) {
                    const float bb = (col < 256) ? bias[col]
                                   : (col < 512) ? bias2[col - 256]
                                                 : bias3[col - 512];
                    const float v = acc[mi][ni][r] + bb;
                    if (col < 256) Cb[(size_t)row * 256 + col] = f2bf(v);
                    else           Cb2[(size_t)row * 384 + (col - 256)] = f2bf(v);
                } else {
                    float v = acc[mi][ni][r] + bias[col];
                    if (RELU) v = fmaxf(v, 0.0f);
                    if (BF16OUT) Cb[(size_t)row * N + col] = f2bf(v);
                }
            }
        }
    }
}

// ---------------------------------------------------------------------------
// Fused GEMM(N=256) + bias + bf16 residual + LayerNorm. DOUBLE-BUFFERED
// (one barrier per K-tile). Tile 64 rows x 256 cols; wave w owns cols
// [w*64,+64). LDS: A 2x8 KB + B 2x32 KB = 80 KB.
// ---------------------------------------------------------------------------
template<bool HASF, bool HASB>
__global__ __launch_bounds__(256)
void mgemm_ln(const unsigned short* __restrict__ A,
              const unsigned short* __restrict__ BT,
              const float* __restrict__ bias,
              const unsigned short* __restrict__ R,   // bf16 residual [*,256]
              const float* __restrict__ g,
              const float* __restrict__ beta,
              float* __restrict__ outF,
              unsigned short* __restrict__ outB,
              int M, int K)
{
    __shared__ __align__(16) unsigned short smemA[2 * 4096];    // 2 bufs x 8 KB
    __shared__ __align__(16) unsigned short smemB[2 * 16384];   // 2 bufs x 32 KB
    const int lane = threadIdx.x & 63;
    const int w    = threadIdx.x >> 6;
    const int lr   = lane & 15, quad = lane >> 4;
    const int bm   = blockIdx.x * 64;
    const int srow = lane >> 2;
    const int selt = (lane & 3) << 3;

    floatx4 acc[4][4];
    #pragma unroll
    for (int i = 0; i < 4; ++i)
        #pragma unroll
        for (int j = 0; j < 4; ++j)
            acc[i][j] = (floatx4){0.f, 0.f, 0.f, 0.f};

    auto stage = [&](int kt, int buf) {
        const int k0 = kt * 64;
        #pragma unroll
        for (int c = 0; c < 2; ++c) {
            const unsigned short* ga = A + (size_t)(bm + w * 16 + srow) * K + k0 + c * 32 + selt;
            __builtin_amdgcn_global_load_lds(AS1C(ga), AS3(smemA + buf * 4096 + c * 2048 + w * 512), 16, 0, 0);
            #pragma unroll
            for (int jj = 0; jj < 4; ++jj) {
                const int j = 4 * w + jj;
                const unsigned short* gb = BT + (size_t)(j * 16 + srow) * K + k0 + c * 32 + selt;
                __builtin_amdgcn_global_load_lds(AS1C(gb), AS3(smemB + buf * 16384 + c * 8192 + j * 512), 16, 0, 0);
            }
        }
    };

    const int NK = K >> 6;
    stage(0, 0);
    for (int kt = 0; kt < NK; ++kt) {
        const int buf = kt & 1;
        __syncthreads();                    // drains loads for buf (issued last iter)
        if (kt + 1 < NK) stage(kt + 1, buf ^ 1);
        #pragma unroll
        for (int c = 0; c < 2; ++c) {
            short8 av[4], bv[4];
            #pragma unroll
            for (int mi = 0; mi < 4; ++mi)
                av[mi] = *(const short8*)&smemA[buf * 4096 + c * 2048 + (mi * 16 + lr) * 32 + quad * 8];
            #pragma unroll
            for (int ni = 0; ni < 4; ++ni)
                bv[ni] = *(const short8*)&smemB[buf * 16384 + c * 8192 + (w * 64 + ni * 16 + lr) * 32 + quad * 8];
            #pragma unroll
            for (int mi = 0; mi < 4; ++mi)
                #pragma unroll
                for (int ni = 0; ni < 4; ++ni)
                    acc[mi][ni] = __builtin_amdgcn_mfma_f32_16x16x32_bf16(
                        av[mi], bv[ni], acc[mi][ni], 0, 0, 0);
        }
    }

    float bs[4], gs[4], bts[4];
    #pragma unroll
    for (int ni = 0; ni < 4; ++ni) {
        const int col = w * 64 + ni * 16 + lr;
        bs[ni] = bias[col]; gs[ni] = g[col]; bts[ni] = beta[col];
    }
    // NK even: last MFMA tile read buf 1, so buf 0's smemA is free for LN
    // scratch without an extra barrier.
    float* lnbuf = (float*)smemA;   // 64 rows x 8 floats = 2 KB

    #pragma unroll
    for (int mi = 0; mi < 4; ++mi) {
        #pragma unroll
        for (int r = 0; r < 4; ++r) {
            const int rl = mi * 16 + quad * 4 + r;
            const int grow = bm + rl;
            const bool act = grow < M;
            float p = 0.f, q = 0.f;
            #pragma unroll
            for (int ni = 0; ni < 4; ++ni) {
                const int col = w * 64 + ni * 16 + lr;
                const float rv = act ? b2f(R[(size_t)grow * 256 + col]) : 0.f;
                const float x = acc[mi][ni][r] + bs[ni] + rv;
                acc[mi][ni][r] = x;
                p += x; q += x * x;
            }
            #pragma unroll
            for (int o = 1; o < 16; o <<= 1) {
                p += __shfl_xor(p, o, 64);
                q += __shfl_xor(q, o, 64);
            }
            if (lr == 0) {
                lnbuf[rl * 8 + 2 * w]     = p;
                lnbuf[rl * 8 + 2 * w + 1] = q;
            }
        }
    }
    __syncthreads();
    #pragma unroll
    for (int mi = 0; mi < 4; ++mi) {
        #pragma unroll
        for (int r = 0; r < 4; ++r) {
            const int rl = mi * 16 + quad * 4 + r;
            const int grow = bm + rl;
            const float4 pa = *(const float4*)&lnbuf[rl * 8];
            const float4 pb = *(const float4*)&lnbuf[rl * 8 + 4];
            const float s  = pa.x + pa.z + pb.x + pb.z;
            const float s2 = pa.y + pa.w + pb.y + pb.w;
            const float mean = s * (1.0f / 256.0f);
            const float var  = s2 * (1.0f / 256.0f) - mean * mean;
            const float rs   = rsqrtf(var + 1e-5f);
            if (grow < M) {
                #pragma unroll
                for (int ni = 0; ni < 4; ++ni) {
                    const int col = w * 64 + ni * 16 + lr;
                    const float y = (acc[mi][ni][r] - mean) * rs * gs[ni] + bts[ni];
                    if (HASF) outF[(size_t)grow * 256 + col] = y;
                    if (HASB) outB[(size_t)grow * 256 + col] = f2bf(y);
                }
            }
        }
    }
}

// ---------------------------------------------------------------------------
// fp32 [M,256] -> bf16 [M_PAD,256] with zero padding rows (layer 0 only)
// ---------------------------------------------------------------------------
__global__ __launch_bounds__(256)
void convpad(const float* __restrict__ X, unsigned short* __restrict__ Y, int M)
{
    const int idx = blockIdx.x * 256 + threadIdx.x;
    const int row = idx >> 6;
    const int c4  = (idx & 63) << 2;
    if (row >= M_PAD) return;
    float4 v = {0.f, 0.f, 0.f, 0.f};
    if (row < M) v = ((const float4*)(X + (size_t)row * 256))[c4 >> 2];
    unsigned p0 = (unsigned)f2bf(v.x) | ((unsigned)f2bf(v.y) << 16);
    unsigned p1 = (unsigned)f2bf(v.z) | ((unsigned)f2bf(v.w) << 16);
    uint2 o; o.x = p0; o.y = p1;
    *(uint2*)(Y + (size_t)row * 256 + c4) = o;
}

// ---------------------------------------------------------------------------
// Merged weight transpose+convert (12 segments, one dispatch).
// ---------------------------------------------------------------------------
struct WJobs {
    const float* W[12];
    unsigned short* WT[12];
    int K[12], N[12], tx[12], start[12];
};

__global__ __launch_bounds__(256)
void wtrans_all(WJobs jb)
{
    __shared__ float t[32][33];
    const int bx = blockIdx.x;
    int seg = 0;
    #pragma unroll
    for (int s = 1; s < 12; ++s) if (bx >= jb.start[s]) seg = s;
    const float* W = jb.W[seg];
    unsigned short* WT = jb.WT[seg];
    const int K = jb.K[seg], N = jb.N[seg], tx = jb.tx[seg];
    const int local = bx - jb.start[seg];
    const int n0 = (local % tx) * 32, k0 = (local / tx) * 32;
    const int c = threadIdx.x & 31, r0 = threadIdx.x >> 5;
    #pragma unroll
    for (int rr = r0; rr < 32; rr += 8)
        t[rr][c] = W[(size_t)(k0 + rr) * N + n0 + c];
    __syncthreads();
    #pragma unroll
    for (int rr = r0; rr < 32; rr += 8)
        WT[(size_t)(n0 + rr) * K + k0 + c] = f2bf(t[c][rr]);
}

// ---------------------------------------------------------------------------
// MSDA, 2-phase. XCD-swizzled block id (grid padded to 3328 = 8*416 so
// same-XCD blocks cover contiguous query ranges under round-robin dispatch).
// Phase B: raw-reinterpret hi-bf16 unpack (no AND), packed float2 fma.
// ---------------------------------------------------------------------------
__global__ __launch_bounds__(256)
void msda_kernel(const unsigned short* __restrict__ valb,
                 const unsigned short* __restrict__ oab,   // [M,384] bf16
                 const float* __restrict__ vr,
                 unsigned short* __restrict__ out)
{
    __shared__ __align__(16) char smeta[8 * 128 * 32];
    const int t = threadIdx.x;
    // XCD swizzle: consecutive blocks round-robin across 8 XCDs; remap so
    // blocks sharing an XCD handle adjacent queries (value-gather L2 reuse).
    const int bid = (blockIdx.x & 7) * 416 + (blockIdx.x >> 3);

    {
        const int wv = t >> 6, lane = t & 63;
        const int lqA = wv * 2 + (lane >> 5);
        const int bq = bid * 8 + lqA;
        const int h = (lane >> 2) & 7;
        const int j = lane & 3;
        if (bq < M_TOT) {
            const int b = (bq >= S_TOT) ? 1 : 0;
            const int q = bq - b * S_TOT;
            const int bofs = b * (S_TOT * 512);
            int Hq, rr, cc, lq;
            if (q < 10000)      { lq = 0; Hq = 100; rr = q / 100;              cc = q - rr * 100; }
            else if (q < 12500) { lq = 1; Hq = 50;  int r2 = q - 10000; rr = r2 / 50; cc = r2 - rr * 50; }
            else if (q < 13125) { lq = 2; Hq = 25;  int r2 = q - 12500; rr = r2 / 25; cc = r2 - rr * 25; }
            else                { lq = 3; Hq = 13;  int r2 = q - 13125; rr = r2 / 13; cc = r2 - rr * 13; }
            const float rxb = (cc + 0.5f) / (vr[(b * 4 + lq) * 2 + 0] * (float)Hq);
            const float ryb = (rr + 0.5f) / (vr[(b * 4 + lq) * 2 + 1] * (float)Hq);
            const int HWt[4] = {100, 50, 25, 13};
            const int stt[4] = {0, 10000, 12500, 13125};
            const int HW = HWt[j], st = stt[j];
            const float fW = (float)HW;
            const float refxw = rxb * vr[(b * 4 + j) * 2 + 0] * fW - 0.5f;
            const float refyw = ryb * vr[(b * 4 + j) * 2 + 1] * fW - 0.5f;
            const unsigned short* row = oab + (size_t)bq * 384;
            const uint2 lgu = *(const uint2*)(row + 256 + h * 16 + j * 4);
            const float l0 = bflo(lgu.x), l1 = bfhi(lgu.x);
            const float l2 = bflo(lgu.y), l3 = bfhi(lgu.y);
            float mx = fmaxf(fmaxf(l0, l1), fmaxf(l2, l3));
            mx = fmaxf(mx, __shfl_xor(mx, 1, 64));
            mx = fmaxf(mx, __shfl_xor(mx, 2, 64));
            const float e0 = __expf(l0 - mx), e1 = __expf(l1 - mx);
            const float e2 = __expf(l2 - mx), e3 = __expf(l3 - mx);
            float ss = e0 + e1 + e2 + e3;
            ss += __shfl_xor(ss, 1, 64);
            ss += __shfl_xor(ss, 2, 64);
            const float inv = 1.0f / ss;
            const uint4 ou = *(const uint4*)(row + h * 32 + j * 8);
            const float oxs[4] = {bflo(ou.x), bflo(ou.y), bflo(ou.z), bflo(ou.w)};
            const float oys[4] = {bfhi(ou.x), bfhi(ou.y), bfhi(ou.z), bfhi(ou.w)};
            const float aw[4]  = {e0 * inv, e1 * inv, e2 * inv, e3 * inv};
            char* mb = smeta + (size_t)(lqA * 128 + h * 16 + j * 4) * 32;
            const int swz = ((h * 4 + j) & 7) << 4;
            #pragma unroll
            for (int p = 0; p < 4; ++p) {
                const float x = refxw + oxs[p];
                const float y = refyw + oys[p];
                const float x0f = floorf(x), y0f = floorf(y);
                const int x0 = (int)x0f, y0 = (int)y0f;
                const float fx = x - x0f, fy = y - y0f;
                const float wb[4] = {(1.f - fx) * (1.f - fy), fx * (1.f - fy),
                                     (1.f - fx) * fy,         fx * fy};
                const int xs[2] = {x0, x0 + 1};
                const int ys2[2] = {y0, y0 + 1};
                int iv[4]; float wv4[4];
                #pragma unroll
                for (int k = 0; k < 4; ++k) {
                    const int xi = xs[k & 1], yi = ys2[k >> 1];
                    const bool vld = ((unsigned)xi < (unsigned)HW) && ((unsigned)yi < (unsigned)HW);
                    const int xc = min(max(xi, 0), HW - 1);
                    const int yc = min(max(yi, 0), HW - 1);
                    iv[k] = bofs + ((st + yc * HW + xc) << 9) + (h << 6);
                    wv4[k] = vld ? wb[k] * aw[p] : 0.0f;
                }
                int4 i4; i4.x = iv[0]; i4.y = iv[1]; i4.z = iv[2]; i4.w = iv[3];
                float4 w4; w4.x = wv4[0]; w4.y = wv4[1]; w4.z = wv4[2]; w4.w = wv4[3];
                *(int4*)(mb + ((p * 32) ^ swz)) = i4;
                *(float4*)(mb + ((p * 32 + 16) ^ swz)) = w4;
            }
        }
    }
    __syncthreads();
    {
        const int lq2 = t >> 5;
        const int r = t & 31;
        const int h2 = r >> 2;
        const int cg = r & 3;
        const int bq2 = bid * 8 + lq2;
        if (bq2 < M_TOT) {
            const char* vbase = (const char*)valb;
            const unsigned cgo = cg * 16;
            floatx2 a0 = {0.f, 0.f}, a1 = {0.f, 0.f}, a2 = {0.f, 0.f}, a3 = {0.f, 0.f};
            const char* mb2 = smeta + (size_t)(lq2 * 128 + h2 * 16) * 32;
            #pragma unroll 4
            for (int s = 0; s < 16; ++s) {
                const int swz2 = ((h2 * 4 + (s >> 2)) & 7) << 4;
                const int4  iv = *(const int4*)(mb2 + ((s * 32) ^ swz2));
                const float4 w4 = *(const float4*)(mb2 + ((s * 32 + 16) ^ swz2));
                const uint4 u0 = *(const uint4*)(vbase + (unsigned)(iv.x + cgo));
                const uint4 u1 = *(const uint4*)(vbase + (unsigned)(iv.y + cgo));
                const uint4 u2 = *(const uint4*)(vbase + (unsigned)(iv.z + cgo));
                const uint4 u3 = *(const uint4*)(vbase + (unsigned)(iv.w + cgo));
                // lo channel: exact (shift); hi channel: raw reinterpret —
                // low-half mantissa garbage is below bf16 rounding scale.
                #define ACC8(UU, WW) { \
                    const floatx2 w2 = {WW, WW}; \
                    const floatx2 t0 = {bflo(UU.x), braw(UU.x)}; \
                    const floatx2 t1 = {bflo(UU.y), braw(UU.y)}; \
                    const floatx2 t2 = {bflo(UU.z), braw(UU.z)}; \
                    const floatx2 t3 = {bflo(UU.w), braw(UU.w)}; \
                    a0 += w2 * t0; a1 += w2 * t1; a2 += w2 * t2; a3 += w2 * t3; }
                ACC8(u0, w4.x) ACC8(u1, w4.y) ACC8(u2, w4.z) ACC8(u3, w4.w)
                #undef ACC8
            }
            uint4 o;
            o.x = (unsigned)f2bf(a0.x) | ((unsigned)f2bf(a0.y) << 16);
            o.y = (unsigned)f2bf(a1.x) | ((unsigned)f2bf(a1.y) << 16);
            o.z = (unsigned)f2bf(a2.x) | ((unsigned)f2bf(a2.y) << 16);
            o.w = (unsigned)f2bf(a3.x) | ((unsigned)f2bf(a3.y) << 16);
            *(uint4*)(out + (size_t)bq2 * 256 + h2 * 32 + cg * 8) = o;
        }
    }
}

// ---------------------------------------------------------------------------
// Host-side orchestration
// ---------------------------------------------------------------------------
extern "C" void kernel_launch(void* const* d_in, const int* in_sizes, int n_in,
                              void* d_out, int out_size, void* d_ws, size_t ws_size,
                              hipStream_t stream)
{
    const float* src    = (const float*)d_in[0];
    const float* vr     = (const float*)d_in[2];
    const float* W_off  = (const float*)d_in[3];
    const float* b_off  = (const float*)d_in[4];
    const float* W_attn = (const float*)d_in[5];
    const float* b_attn = (const float*)d_in[6];
    const float* W_val  = (const float*)d_in[7];
    const float* b_val  = (const float*)d_in[8];
    const float* W_out  = (const float*)d_in[9];
    const float* b_out  = (const float*)d_in[10];
    const float* ln1_g  = (const float*)d_in[11];
    const float* ln1_b  = (const float*)d_in[12];
    const float* W1     = (const float*)d_in[13];
    const float* b1     = (const float*)d_in[14];
    const float* W2     = (const float*)d_in[15];
    const float* b2     = (const float*)d_in[16];
    const float* ln2_g  = (const float*)d_in[17];
    const float* ln2_b  = (const float*)d_in[18];
    float* out = (float*)d_out;

    const int M = M_TOT;

    // --- workspace (bytes), total 112,066,560 ---
    // [0,          54,525,952)  HBF bf16 [M_PAD,1024]; overlays:
    //     OAB  bf16 [M_PAD,384] at [0, 20,447,232)
    //     VALB bf16 [M_PAD,256] at [20,447,232, 34,078,720)
    // [54,525,952, 68,157,440)  X1B bf16 [M_PAD,256]  (post-LN1, bf16)
    // [81,788,928, 95,420,416)  RB  bf16 [M_PAD,256]  (x input, bf16)
    // [95,420,416,109,051,904)  YBF bf16 [M_PAD,256]  (msda out)
    // [109,051,904,112,066,560) WT  transposed weights
    char* wsb = (char*)d_ws;
    unsigned short* HBF  = (unsigned short*)wsb;
    unsigned short* OAB  = (unsigned short*)wsb;
    unsigned short* VALB = (unsigned short*)(wsb + 20447232);
    unsigned short* X1B  = (unsigned short*)(wsb + 54525952);
    unsigned short* RB   = (unsigned short*)(wsb + 81788928);
    unsigned short* YBF  = (unsigned short*)(wsb + 95420416);
    unsigned short* WT   = (unsigned short*)(wsb + 109051904);

    const size_t LWT = 753664;
    const size_t oProj = 0, oOut = 163840, oW1 = 229376, oW2 = 491520;

    WJobs jb;
    int startAcc = 0;
    for (int i = 0; i < 2; ++i) {
        unsigned short* wt = WT + i * LWT;
        const float* srcs[6] = {W_val + i * 65536, W_off + i * 65536, W_attn + i * 32768,
                                W_out + i * 65536, W1 + i * 262144, W2 + i * 262144};
        unsigned short* dsts[6] = {wt + oProj, wt + oProj + 65536, wt + oProj + 131072,
                                   wt + oOut, wt + oW1, wt + oW2};
        const int Ks[6] = {256, 256, 256, 256, 256, 1024};
        const int Ns[6] = {256, 256, 128, 256, 1024, 256};
        for (int s = 0; s < 6; ++s) {
            const int idx = i * 6 + s;
            jb.W[idx] = srcs[s]; jb.WT[idx] = dsts[s];
            jb.K[idx] = Ks[s]; jb.N[idx] = Ns[s]; jb.tx[idx] = Ns[s] / 32;
            jb.start[idx] = startAcc;
            startAcc += (Ns[s] / 32) * (Ks[s] / 32);
        }
    }
    wtrans_all<<<dim3(startAcc), 256, 0, stream>>>(jb);

    const int GM128 = M_PAD / 128;  // 208
    const int GM64  = M_PAD / 64;   // 416
    const dim3 blk(256);

    for (int i = 0; i < 2; ++i) {
        unsigned short* wt = WT + i * LWT;

        if (i == 0)
            convpad<<<dim3(M_PAD / 4), blk, 0, stream>>>(src, RB, M);

        // merged projections: N=640 -> VALB (bf16) + OAB (bf16)
        mgemm<64, false, false, true><<<dim3(5, GM64), blk, 0, stream>>>(
            RB, wt + oProj, b_val + i * 256, b_off + i * 256, b_attn + i * 128,
            VALB, OAB, M, 640, 256);

        // deformable sampling (grid padded to 8*416 for the XCD swizzle)
        msda_kernel<<<dim3(3328), blk, 0, stream>>>(VALB, OAB, vr, YBF);

        // fused out-proj + residual(RB bf16) + LN1 -> X1B (bf16 only)
        mgemm_ln<false, true><<<dim3(GM64), blk, 0, stream>>>(
            YBF, wt + oOut, b_out + i * 256, RB,
            ln1_g + i * 256, ln1_b + i * 256, nullptr, X1B, M, 256);

        // FFN1 (relu, bf16 hidden overlays OAB+VALB region)
        mgemm<128, true, true, false><<<dim3(8, GM128), blk, 0, stream>>>(
            X1B, wt + oW1, b1 + i * 1024, nullptr, nullptr,
            HBF, nullptr, M, 1024, 256);

        // fused FFN2 + residual(X1B bf16) + LN2:
        //   layer 0 -> RB (bf16, next layer's x); layer 1 -> out (f32)
        if (i == 0)
            mgemm_ln<false, true><<<dim3(GM64), blk, 0, stream>>>(
                HBF, wt + oW2, b2 + i * 256, X1B,
                ln2_g + i * 256, ln2_b + i * 256, nullptr, RB, M, 1024);
        else
            mgemm_ln<true, false><<<dim3(GM64), blk, 0, stream>>>(
                HBF, wt + oW2, b2 + i * 256, X1B,
                ln2_g + i * 256, ln2_b + i * 256, out, nullptr, M, 1024);
    }
}